// Round 1
// baseline (847.907 us; speedup 1.0000x reference)
//
#include <hip/hip_runtime.h>
#include <hip/hip_bf16.h>

// MockLlamaAttention: B=1, S=2048, HIDDEN=4096, H=32, HKV=8, D=128, GQA G=4.
// Pipeline: cvt(hs->f16) | rope tables | GEMM q/k/v (f16 MFMA, W converted on
// stage) | rope apply | flash attention (swapped-QK^T / swapped-PV) | GEMM out.
// Workspace: 41 MB (o_h aliases hs_h which is dead after the V projection).

typedef _Float16 half4_t __attribute__((ext_vector_type(4)));
typedef _Float16 half8_t __attribute__((ext_vector_type(8)));
typedef float f32x4 __attribute__((ext_vector_type(4)));

#define S_LEN 2048
#define HID 4096
#define NH 32
#define NKV 8

// ---------------- fp32 -> f16 convert (vectorized) ----------------
__global__ __launch_bounds__(256) void cvt_f32_f16(const float* __restrict__ src,
                                                   _Float16* __restrict__ dst, int n4) {
  int i = blockIdx.x * 256 + threadIdx.x;
  if (i >= n4) return;
  f32x4 v = *(const f32x4*)(src + (size_t)i * 4);
  half4_t h = {(_Float16)v[0], (_Float16)v[1], (_Float16)v[2], (_Float16)v[3]};
  *(half4_t*)(dst + (size_t)i * 4) = h;
}

// ---------------- RoPE cos/sin table: [2048][64] fp32 ----------------
__global__ __launch_bounds__(256) void rope_table_kernel(float* __restrict__ cost,
                                                         float* __restrict__ sint) {
  int i = blockIdx.x * 256 + threadIdx.x;  // 2048*64 exact
  int d = i & 63;
  int s = i >> 6;
  // inv_freq = 10000^(-d/64) = 2^(-d/64 * log2(10000))
  float inv = exp2f(-(float)d * (13.287712379549449f / 64.0f));
  float f = (float)s * inv;
  cost[i] = cosf(f);
  sint[i] = sinf(f);
}

// ---------------- RoPE apply (rotate_half), in place on f16 [S][heads*128] ----
__global__ __launch_bounds__(256) void rope_apply_kernel(_Float16* __restrict__ X,
                                                         const float* __restrict__ cost,
                                                         const float* __restrict__ sint,
                                                         int heads) {
  int idx = blockIdx.x * 256 + threadIdx.x;  // S*heads*16 exact
  int g = idx & 15;                          // 4-pair group within head dim
  int tmp = idx >> 4;
  int h = tmp % heads;
  int s = tmp / heads;
  int d0 = g * 4;
  size_t base = (size_t)s * (heads * 128) + h * 128 + d0;
  half4_t x1 = *(half4_t*)(X + base);
  half4_t x2 = *(half4_t*)(X + base + 64);
  const float* cp = cost + s * 64 + d0;
  const float* sp = sint + s * 64 + d0;
  half4_t y1, y2;
#pragma unroll
  for (int j = 0; j < 4; ++j) {
    float c = cp[j], sn = sp[j];
    float a = (float)x1[j], b = (float)x2[j];
    y1[j] = (_Float16)(a * c - b * sn);
    y2[j] = (_Float16)(b * c + a * sn);
  }
  *(half4_t*)(X + base) = y1;
  *(half4_t*)(X + base + 64) = y2;
}

// ---------------- GEMM: C[M,N] = A[M,K](f16) @ W[N,K](f32)^T ----------------
// 128x128 tile, BK=32, 256 threads (4 waves, each 64x64 as 4x4 16x16 frags).
// W converted fp32->f16 during LDS staging (weights are read exactly once).
template <bool OUTF32>
__global__ __launch_bounds__(256) void gemm_xwt(const _Float16* __restrict__ A,
                                                const float* __restrict__ W,
                                                void* __restrict__ Cout,
                                                int M, int N, int K) {
  constexpr int LDK = 40;  // 32 + 8 pad (keeps 16B align, breaks bank conflicts)
  __shared__ __align__(16) _Float16 As[128 * LDK];
  __shared__ __align__(16) _Float16 Bs[128 * LDK];
  const int t = threadIdx.x;
  const int w = t >> 6;
  const int l = t & 63;
  const int lr = l & 15;
  const int lg = l >> 4;
  const int m0 = blockIdx.y * 128;
  const int n0 = blockIdx.x * 128;
  const int wm = (w >> 1) * 64;
  const int wn = (w & 1) * 64;
  const int sr = t >> 2;        // staging row 0..63
  const int sc = (t & 3) * 8;   // staging col (8 halfs = 16B)
  f32x4 acc[4][4] = {};

  for (int kb = 0; kb < K; kb += 32) {
#pragma unroll
    for (int it = 0; it < 2; ++it) {  // stage A tile (f16 source)
      int r = sr + it * 64;
      half8_t av = *(const half8_t*)(A + (size_t)(m0 + r) * K + kb + sc);
      *(half8_t*)(As + r * LDK + sc) = av;
    }
#pragma unroll
    for (int it = 0; it < 2; ++it) {  // stage B tile (fp32 source, convert)
      int r = sr + it * 64;
      const float* wp = W + (size_t)(n0 + r) * K + kb + sc;
      f32x4 w0 = *(const f32x4*)wp;
      f32x4 w1 = *(const f32x4*)(wp + 4);
      half8_t bv = {(_Float16)w0[0], (_Float16)w0[1], (_Float16)w0[2], (_Float16)w0[3],
                    (_Float16)w1[0], (_Float16)w1[1], (_Float16)w1[2], (_Float16)w1[3]};
      *(half8_t*)(Bs + r * LDK + sc) = bv;
    }
    __syncthreads();
    half8_t af[4], bf[4];
#pragma unroll
    for (int mi = 0; mi < 4; ++mi)
      af[mi] = *(const half8_t*)(As + (wm + mi * 16 + lr) * LDK + lg * 8);
#pragma unroll
    for (int ni = 0; ni < 4; ++ni)
      bf[ni] = *(const half8_t*)(Bs + (wn + ni * 16 + lr) * LDK + lg * 8);
#pragma unroll
    for (int mi = 0; mi < 4; ++mi)
#pragma unroll
      for (int ni = 0; ni < 4; ++ni)
        acc[mi][ni] = __builtin_amdgcn_mfma_f32_16x16x32_f16(af[mi], bf[ni], acc[mi][ni], 0, 0, 0);
    __syncthreads();
  }

#pragma unroll
  for (int mi = 0; mi < 4; ++mi) {
#pragma unroll
    for (int ni = 0; ni < 4; ++ni) {
      int row = m0 + wm + mi * 16 + lg * 4;  // D: row=(l>>4)*4+i, col=l&15
      int col = n0 + wn + ni * 16 + lr;
#pragma unroll
      for (int i = 0; i < 4; ++i) {
        if (OUTF32)
          ((float*)Cout)[(size_t)(row + i) * N + col] = acc[mi][ni][i];
        else
          ((_Float16*)Cout)[(size_t)(row + i) * N + col] = (_Float16)acc[mi][ni][i];
      }
    }
  }
}

// ---------------- Flash attention (causal, GQA) ----------------
// 1 wave per (q-tile of 16 rows, head). Swapped QK^T: S^T = mfma(K, Q) puts
// q at lane&15 (lane-local softmax state). Swapped PV: acc^T = mfma(V^T, P^T);
// the S^T D-fragment IS the P^T B-fragment for 16x16x16 (b==i), no shuffles.
__global__ __launch_bounds__(64) void attn_kernel(const _Float16* __restrict__ Q,
                                                  const _Float16* __restrict__ K,
                                                  const _Float16* __restrict__ V,
                                                  _Float16* __restrict__ O) {
  const int qt = blockIdx.x;   // 0..127
  const int h = blockIdx.y;    // 0..31
  const int hk = h >> 2;       // GQA: 4 q-heads per kv-head
  const int l = threadIdx.x;
  const int lr = l & 15;
  const int lg = l >> 4;
  const float scale = 0.08838834764831845f;  // 1/sqrt(128)
  const float LOG2E = 1.4426950408889634f;
  const float NEG = -1.0e30f;
  const int sq = qt * 16 + lr;  // this lane's q row (column of S^T)

  half8_t qf[4];
#pragma unroll
  for (int c = 0; c < 4; ++c)
    qf[c] = *(const half8_t*)(Q + (size_t)sq * HID + h * 128 + c * 32 + lg * 8);

  f32x4 acc[8];
#pragma unroll
  for (int dc = 0; dc < 8; ++dc) acc[dc] = (f32x4){0.f, 0.f, 0.f, 0.f};
  float m = NEG, denom = 0.0f;

  for (int kt = 0; kt <= qt; ++kt) {
    // S^T[key][q] over 16 keys x 16 q, K-dim = 128 (4 chunks of 32)
    f32x4 s = (f32x4){0.f, 0.f, 0.f, 0.f};
    const int kr = kt * 16 + lr;
#pragma unroll
    for (int c = 0; c < 4; ++c) {
      half8_t kf = *(const half8_t*)(K + (size_t)kr * (NKV * 128) + hk * 128 + c * 32 + lg * 8);
      s = __builtin_amdgcn_mfma_f32_16x16x32_f16(kf, qf[c], s, 0, 0, 0);
    }
    const int kbase = kt * 16 + lg * 4;  // this lane's key rows: kbase+i
    float sc[4];
#pragma unroll
    for (int i = 0; i < 4; ++i) {
      sc[i] = s[i] * scale;
      if (kbase + i > sq) sc[i] = NEG;  // causal mask
    }
    float tmax = fmaxf(fmaxf(sc[0], sc[1]), fmaxf(sc[2], sc[3]));
    tmax = fmaxf(tmax, __shfl_xor(tmax, 16));
    tmax = fmaxf(tmax, __shfl_xor(tmax, 32));
    const float mnew = fmaxf(m, tmax);
    const float corr = exp2f((m - mnew) * LOG2E);
    float p[4], ps = 0.f;
#pragma unroll
    for (int i = 0; i < 4; ++i) {
      p[i] = exp2f((sc[i] - mnew) * LOG2E);
      ps += p[i];
    }
    ps += __shfl_xor(ps, 16);
    ps += __shfl_xor(ps, 32);
    denom = denom * corr + ps;
    m = mnew;
    half4_t pf = {(_Float16)p[0], (_Float16)p[1], (_Float16)p[2], (_Float16)p[3]};
#pragma unroll
    for (int dc = 0; dc < 8; ++dc) {
#pragma unroll
      for (int i = 0; i < 4; ++i) acc[dc][i] *= corr;
      half4_t vf;  // V^T A-frag: V[kbase+b][dc*16+lr]
#pragma unroll
      for (int b = 0; b < 4; ++b)
        vf[b] = V[(size_t)(kbase + b) * (NKV * 128) + hk * 128 + dc * 16 + lr];
      acc[dc] = __builtin_amdgcn_mfma_f32_16x16x16f16(vf, pf, acc[dc], 0, 0, 0);
    }
  }
  const float inv = 1.0f / denom;
#pragma unroll
  for (int dc = 0; dc < 8; ++dc)
#pragma unroll
    for (int i = 0; i < 4; ++i)
      O[(size_t)sq * HID + h * 128 + dc * 16 + lg * 4 + i] = (_Float16)(acc[dc][i] * inv);
}

// ---------------- launcher ----------------
extern "C" void kernel_launch(void* const* d_in, const int* in_sizes, int n_in,
                              void* d_out, int out_size, void* d_ws, size_t ws_size,
                              hipStream_t stream) {
  (void)in_sizes; (void)n_in; (void)out_size; (void)ws_size;
  const float* hs = (const float*)d_in[0];
  const float* wq = (const float*)d_in[1];
  const float* wk = (const float*)d_in[2];
  const float* wv = (const float*)d_in[3];
  const float* wo = (const float*)d_in[4];

  char* ws = (char*)d_ws;
  _Float16* hs_h = (_Float16*)(ws);                      // 16 MB [0,16M)
  _Float16* q_h  = (_Float16*)(ws + (16u << 20));        // 16 MB
  _Float16* k_h  = (_Float16*)(ws + (32u << 20));        // 4 MB
  _Float16* v_h  = (_Float16*)(ws + (36u << 20));        // 4 MB
  _Float16* o_h  = hs_h;                                 // alias: hs dead after V proj
  float* cost    = (float*)(ws + (40u << 20));           // 512 KB
  float* sint    = (float*)(ws + (40u << 20) + (512u << 10));  // 512 KB; total 41 MB

  const int nhs = S_LEN * HID;  // 8388608
  cvt_f32_f16<<<nhs / 4 / 256, 256, 0, stream>>>(hs, hs_h, nhs / 4);
  rope_table_kernel<<<(S_LEN * 64) / 256, 256, 0, stream>>>(cost, sint);

  gemm_xwt<false><<<dim3(HID / 128, S_LEN / 128), 256, 0, stream>>>(hs_h, wq, q_h, S_LEN, HID, HID);
  gemm_xwt<false><<<dim3(NKV * 128 / 128, S_LEN / 128), 256, 0, stream>>>(hs_h, wk, k_h, S_LEN, NKV * 128, HID);
  gemm_xwt<false><<<dim3(NKV * 128 / 128, S_LEN / 128), 256, 0, stream>>>(hs_h, wv, v_h, S_LEN, NKV * 128, HID);

  rope_apply_kernel<<<(S_LEN * NH * 16) / 256, 256, 0, stream>>>(q_h, cost, sint, NH);
  rope_apply_kernel<<<(S_LEN * NKV * 16) / 256, 256, 0, stream>>>(k_h, cost, sint, NKV);

  attn_kernel<<<dim3(S_LEN / 16, NH), 64, 0, stream>>>(q_h, k_h, v_h, o_h);

  gemm_xwt<true><<<dim3(HID / 128, S_LEN / 128), 256, 0, stream>>>(o_h, wo, d_out, S_LEN, HID, HID);
}

// Round 2
// 607.126 us; speedup vs baseline: 1.3966x; 1.3966x over previous
//
#include <hip/hip_runtime.h>
#include <hip/hip_bf16.h>

// MockLlamaAttention R2: B=1, S=2048, HIDDEN=4096, H=32, HKV=8, D=128, G=4.
// Changes vs R1: (a) m97-style GEMMs (f16 weights pre-converted, global_load_lds
// width-16 staging, linear LDS); (b) V-projection writes V^T directly;
// (c) attention: 4-wave blocks (GQA group shares K/V via L1), 32 q-rows/wave,
// vectorized V^T loads, defer-max rescale, XCD-affine + heavy-first scheduling.
// Workspace usage: 73 MiB.

typedef _Float16 half4_t __attribute__((ext_vector_type(4)));
typedef _Float16 half8_t __attribute__((ext_vector_type(8)));
typedef float f32x4 __attribute__((ext_vector_type(4)));

#define S_LEN 2048
#define HID 4096
#define NH 32
#define NKV 8

__device__ __forceinline__ void gload_lds16(const void* g, void* l) {
  __builtin_amdgcn_global_load_lds((const __attribute__((address_space(1))) void*)g,
                                   (__attribute__((address_space(3))) void*)l, 16, 0, 0);
}

// ---------------- fp32 -> f16 convert (vectorized) ----------------
__global__ __launch_bounds__(256) void cvt_f32_f16(const float* __restrict__ src,
                                                   _Float16* __restrict__ dst, int n4) {
  int i = blockIdx.x * 256 + threadIdx.x;
  if (i >= n4) return;
  f32x4 v = *(const f32x4*)(src + (size_t)i * 4);
  half4_t h = {(_Float16)v[0], (_Float16)v[1], (_Float16)v[2], (_Float16)v[3]};
  *(half4_t*)(dst + (size_t)i * 4) = h;
}

// ---------------- RoPE cos/sin table: [2048][64] fp32 ----------------
__global__ __launch_bounds__(256) void rope_table_kernel(float* __restrict__ cost,
                                                         float* __restrict__ sint) {
  int i = blockIdx.x * 256 + threadIdx.x;
  int d = i & 63;
  int s = i >> 6;
  float inv = exp2f(-(float)d * (13.287712379549449f / 64.0f));
  float f = (float)s * inv;
  cost[i] = cosf(f);
  sint[i] = sinf(f);
}

// ---------------- RoPE apply (rotate_half), in place on f16 [S][heads*128] ----
__global__ __launch_bounds__(256) void rope_apply_kernel(_Float16* __restrict__ X,
                                                         const float* __restrict__ cost,
                                                         const float* __restrict__ sint,
                                                         int heads) {
  int idx = blockIdx.x * 256 + threadIdx.x;
  int g = idx & 15;
  int tmp = idx >> 4;
  int h = tmp % heads;
  int s = tmp / heads;
  int d0 = g * 4;
  size_t base = (size_t)s * (heads * 128) + h * 128 + d0;
  half4_t x1 = *(half4_t*)(X + base);
  half4_t x2 = *(half4_t*)(X + base + 64);
  const float* cp = cost + s * 64 + d0;
  const float* sp = sint + s * 64 + d0;
  half4_t y1, y2;
#pragma unroll
  for (int j = 0; j < 4; ++j) {
    float c = cp[j], sn = sp[j];
    float a = (float)x1[j], b = (float)x2[j];
    y1[j] = (_Float16)(a * c - b * sn);
    y2[j] = (_Float16)(b * c + a * sn);
  }
  *(half4_t*)(X + base) = y1;
  *(half4_t*)(X + base + 64) = y2;
}

// ---------------- GEMM (m97 structure): C[M,N] = A[M,K]f16 @ W[N,K]f16^T ------
// 128x128 tile, BK=32, 256 threads, global_load_lds(16B) staging, linear LDS.
template <int MODE>  // 0: f16 C, 1: f32 C
__global__ __launch_bounds__(256) void gemm_h(const _Float16* __restrict__ A,
                                              const _Float16* __restrict__ W,
                                              void* __restrict__ Cout,
                                              int M, int N, int K) {
  __shared__ __align__(16) _Float16 As[128 * 32];
  __shared__ __align__(16) _Float16 Bs[128 * 32];
  const int t = threadIdx.x, w = t >> 6, l = t & 63, lr = l & 15, lg = l >> 4;
  const int m0 = blockIdx.y * 128, n0 = blockIdx.x * 128;
  const int wm = (w >> 1) * 64, wn = (w & 1) * 64;
  const int srow = l >> 2, scol = (l & 3) * 8;
  f32x4 acc[4][4] = {};
  const _Float16* ap = A + (size_t)m0 * K + scol;
  const _Float16* bp = W + (size_t)n0 * K + scol;

  for (int kb = 0; kb < K; kb += 32) {
#pragma unroll
    for (int it = 0; it < 2; ++it) {
      const int ci = it * 4 + w;           // LDS chunk 0..7 (1 KiB each)
      const int r = ci * 16 + srow;        // tile row this lane stages
      gload_lds16(ap + (size_t)r * K + kb, As + ci * 512);
      gload_lds16(bp + (size_t)r * K + kb, Bs + ci * 512);
    }
    __syncthreads();
    half8_t af[4], bf[4];
#pragma unroll
    for (int mi = 0; mi < 4; ++mi)
      af[mi] = *(const half8_t*)(As + (wm + mi * 16 + lr) * 32 + lg * 8);
#pragma unroll
    for (int ni = 0; ni < 4; ++ni)
      bf[ni] = *(const half8_t*)(Bs + (wn + ni * 16 + lr) * 32 + lg * 8);
#pragma unroll
    for (int mi = 0; mi < 4; ++mi)
#pragma unroll
      for (int ni = 0; ni < 4; ++ni)
        acc[mi][ni] = __builtin_amdgcn_mfma_f32_16x16x32_f16(af[mi], bf[ni], acc[mi][ni], 0, 0, 0);
    __syncthreads();
  }

#pragma unroll
  for (int mi = 0; mi < 4; ++mi) {
#pragma unroll
    for (int ni = 0; ni < 4; ++ni) {
      int row = m0 + wm + mi * 16 + lg * 4;
      int col = n0 + wn + ni * 16 + lr;
#pragma unroll
      for (int i = 0; i < 4; ++i) {
        if (MODE == 1)
          ((float*)Cout)[(size_t)(row + i) * N + col] = acc[mi][ni][i];
        else
          ((_Float16*)Cout)[(size_t)(row + i) * N + col] = (_Float16)acc[mi][ni][i];
      }
    }
  }
}

// ---------------- fused K/V projection; V written transposed -----------------
// grid (16,16): bx<8 -> K cols, bx>=8 -> V cols. Ck [2048][1024], Vt [1024][2048].
__global__ __launch_bounds__(256) void gemm_kv(const _Float16* __restrict__ A,
                                               const _Float16* __restrict__ Wk,
                                               const _Float16* __restrict__ Wv,
                                               _Float16* __restrict__ Ck,
                                               _Float16* __restrict__ Vt) {
  __shared__ __align__(16) _Float16 As[128 * 32];
  __shared__ __align__(16) _Float16 Bs[128 * 32];
  const int K = HID;
  const int t = threadIdx.x, w = t >> 6, l = t & 63, lr = l & 15, lg = l >> 4;
  const bool isv = blockIdx.x >= 8;
  const int m0 = blockIdx.y * 128, n0 = (blockIdx.x & 7) * 128;
  const _Float16* W = isv ? Wv : Wk;
  const int wm = (w >> 1) * 64, wn = (w & 1) * 64;
  const int srow = l >> 2, scol = (l & 3) * 8;
  f32x4 acc[4][4] = {};
  const _Float16* ap = A + (size_t)m0 * K + scol;
  const _Float16* bp = W + (size_t)n0 * K + scol;

  for (int kb = 0; kb < K; kb += 32) {
#pragma unroll
    for (int it = 0; it < 2; ++it) {
      const int ci = it * 4 + w;
      const int r = ci * 16 + srow;
      gload_lds16(ap + (size_t)r * K + kb, As + ci * 512);
      gload_lds16(bp + (size_t)r * K + kb, Bs + ci * 512);
    }
    __syncthreads();
    half8_t af[4], bf[4];
#pragma unroll
    for (int mi = 0; mi < 4; ++mi)
      af[mi] = *(const half8_t*)(As + (wm + mi * 16 + lr) * 32 + lg * 8);
#pragma unroll
    for (int ni = 0; ni < 4; ++ni)
      bf[ni] = *(const half8_t*)(Bs + (wn + ni * 16 + lr) * 32 + lg * 8);
#pragma unroll
    for (int mi = 0; mi < 4; ++mi)
#pragma unroll
      for (int ni = 0; ni < 4; ++ni)
        acc[mi][ni] = __builtin_amdgcn_mfma_f32_16x16x32_f16(af[mi], bf[ni], acc[mi][ni], 0, 0, 0);
    __syncthreads();
  }

#pragma unroll
  for (int mi = 0; mi < 4; ++mi) {
#pragma unroll
    for (int ni = 0; ni < 4; ++ni) {
      int row = m0 + wm + mi * 16 + lg * 4;
      int col = n0 + wn + ni * 16 + lr;
      if (!isv) {
#pragma unroll
        for (int i = 0; i < 4; ++i)
          Ck[(size_t)(row + i) * (NKV * 128) + col] = (_Float16)acc[mi][ni][i];
      } else {
        half4_t o;
#pragma unroll
        for (int i = 0; i < 4; ++i) o[i] = (_Float16)acc[mi][ni][i];
        *(half4_t*)(Vt + (size_t)col * S_LEN + row) = o;  // V^T[feat][seq]
      }
    }
  }
}

// ---------------- Flash attention v2 (causal, GQA) ----------------
// Block = 4 waves = 4 q-heads of one kv group (shared K/V -> L1 broadcast).
// Wave: 32 q rows (2 fragments). Swapped QK^T (S^T=mfma(K,Q)), swapped PV
// (acc^T = mfma(V^T, P^T)) with V pre-transposed -> half4 vector A-frag loads.
__global__ __launch_bounds__(256) void attn_kernel(const _Float16* __restrict__ Q,
                                                   const _Float16* __restrict__ K,
                                                   const _Float16* __restrict__ Vt,
                                                   _Float16* __restrict__ O) {
  const int bid = blockIdx.x;
  const int hk = bid & 7;            // XCD-affine kv head
  const int qt = 63 - (bid >> 3);    // heaviest q-tiles dispatched first
  const int w = threadIdx.x >> 6;
  const int h = hk * 4 + w;
  const int l = threadIdx.x & 63;
  const int lr = l & 15;
  const int lg = l >> 4;
  const float scale = 0.08838834764831845f;  // 1/sqrt(128)
  const float LOG2E = 1.4426950408889634f;
  const float NEG = -1.0e30f;

  int sq[2];
  half8_t qf[2][4];
#pragma unroll
  for (int qc = 0; qc < 2; ++qc) {
    sq[qc] = qt * 32 + qc * 16 + lr;
#pragma unroll
    for (int c = 0; c < 4; ++c)
      qf[qc][c] = *(const half8_t*)(Q + (size_t)sq[qc] * HID + h * 128 + c * 32 + lg * 8);
  }
  f32x4 acc[8][2] = {};
  float m[2] = {NEG, NEG};
  float den[2] = {0.f, 0.f};

  const int ktend = qt * 2 + 2;
  for (int kt = 0; kt < ktend; ++kt) {
    const int kr = kt * 16 + lr;
    half8_t kf[4];
#pragma unroll
    for (int c = 0; c < 4; ++c)
      kf[c] = *(const half8_t*)(K + (size_t)kr * (NKV * 128) + hk * 128 + c * 32 + lg * 8);
    f32x4 s0 = {0.f, 0.f, 0.f, 0.f}, s1 = {0.f, 0.f, 0.f, 0.f};
#pragma unroll
    for (int c = 0; c < 4; ++c) {
      s0 = __builtin_amdgcn_mfma_f32_16x16x32_f16(kf[c], qf[0][c], s0, 0, 0, 0);
      s1 = __builtin_amdgcn_mfma_f32_16x16x32_f16(kf[c], qf[1][c], s1, 0, 0, 0);
    }
    const int kbase = kt * 16 + lg * 4;
    float sc[2][4];
#pragma unroll
    for (int i = 0; i < 4; ++i) {
      sc[0][i] = s0[i] * scale;
      sc[1][i] = s1[i] * scale;
    }
    if (kt >= 2 * qt) {  // only the last two kt steps can hit the causal edge
#pragma unroll
      for (int qc = 0; qc < 2; ++qc)
#pragma unroll
        for (int i = 0; i < 4; ++i)
          if (kbase + i > sq[qc]) sc[qc][i] = NEG;
    }
    half4_t pf[2];
#pragma unroll
    for (int qc = 0; qc < 2; ++qc) {
      float mx = fmaxf(fmaxf(sc[qc][0], sc[qc][1]), fmaxf(sc[qc][2], sc[qc][3]));
      mx = fmaxf(mx, __shfl_xor(mx, 16));
      mx = fmaxf(mx, __shfl_xor(mx, 32));
      if (!__all(mx - m[qc] <= 8.0f)) {  // defer-max (T13, THR=8)
        float mn = fmaxf(m[qc], mx);
        float corr = exp2f((m[qc] - mn) * LOG2E);
        den[qc] *= corr;
#pragma unroll
        for (int dc = 0; dc < 8; ++dc)
#pragma unroll
          for (int i = 0; i < 4; ++i) acc[dc][qc][i] *= corr;
        m[qc] = mn;
      }
      float ps = 0.f, p[4];
#pragma unroll
      for (int i = 0; i < 4; ++i) {
        p[i] = exp2f((sc[qc][i] - m[qc]) * LOG2E);
        ps += p[i];
      }
      ps += __shfl_xor(ps, 16);
      ps += __shfl_xor(ps, 32);
      den[qc] += ps;
      pf[qc] = (half4_t){(_Float16)p[0], (_Float16)p[1], (_Float16)p[2], (_Float16)p[3]};
    }
#pragma unroll
    for (int dc = 0; dc < 8; ++dc) {
      half4_t vf = *(const half4_t*)(Vt + (size_t)(hk * 128 + dc * 16 + lr) * S_LEN + kt * 16 + lg * 4);
      acc[dc][0] = __builtin_amdgcn_mfma_f32_16x16x16f16(vf, pf[0], acc[dc][0], 0, 0, 0);
      acc[dc][1] = __builtin_amdgcn_mfma_f32_16x16x16f16(vf, pf[1], acc[dc][1], 0, 0, 0);
    }
  }

#pragma unroll
  for (int qc = 0; qc < 2; ++qc) {
    float inv = 1.0f / den[qc];
#pragma unroll
    for (int dc = 0; dc < 8; ++dc) {
      half4_t o;
#pragma unroll
      for (int i = 0; i < 4; ++i) o[i] = (_Float16)(acc[dc][qc][i] * inv);
      *(half4_t*)(O + (size_t)sq[qc] * HID + h * 128 + dc * 16 + lg * 4) = o;
    }
  }
}

// ---------------- launcher ----------------
extern "C" void kernel_launch(void* const* d_in, const int* in_sizes, int n_in,
                              void* d_out, int out_size, void* d_ws, size_t ws_size,
                              hipStream_t stream) {
  (void)in_sizes; (void)n_in; (void)out_size; (void)ws_size;
  const float* hs = (const float*)d_in[0];
  const float* wq = (const float*)d_in[1];
  const float* wk = (const float*)d_in[2];
  const float* wv = (const float*)d_in[3];
  const float* wo = (const float*)d_in[4];

  char* ws = (char*)d_ws;
  _Float16* hs_h = (_Float16*)(ws);                       // 16 MiB
  _Float16* q_h  = (_Float16*)(ws + (16u << 20));         // 16 MiB
  _Float16* k_h  = (_Float16*)(ws + (32u << 20));         // 4 MiB
  _Float16* Vt   = (_Float16*)(ws + (36u << 20));         // 4 MiB [1024][2048]
  float* cost    = (float*)(ws + (40u << 20));            // 512 KiB
  float* sint    = (float*)(ws + (40u << 20) + (512u << 10));
  _Float16* wbuf = (_Float16*)(ws + (41u << 20));         // 32 MiB reused f16 weights
  _Float16* wbuf2 = wbuf + (8u << 20) / 2;                // +8 MiB (wv half)
  _Float16* o_h  = hs_h;                                  // alias: hs dead after KV proj

  cvt_f32_f16<<<8192, 256, 0, stream>>>(hs, hs_h, (S_LEN * HID) / 4);
  rope_table_kernel<<<(S_LEN * 64) / 256, 256, 0, stream>>>(cost, sint);

  // Q projection
  cvt_f32_f16<<<16384, 256, 0, stream>>>(wq, wbuf, (HID * HID) / 4);
  gemm_h<0><<<dim3(32, 16), 256, 0, stream>>>(hs_h, wbuf, q_h, S_LEN, HID, HID);

  // K + V projections (V transposed on store)
  cvt_f32_f16<<<4096, 256, 0, stream>>>(wk, wbuf, (NKV * 128 * HID) / 4);
  cvt_f32_f16<<<4096, 256, 0, stream>>>(wv, wbuf2, (NKV * 128 * HID) / 4);
  gemm_kv<<<dim3(16, 16), 256, 0, stream>>>(hs_h, wbuf, wbuf2, k_h, Vt);

  rope_apply_kernel<<<(S_LEN * NH * 16) / 256, 256, 0, stream>>>(q_h, cost, sint, NH);
  rope_apply_kernel<<<(S_LEN * NKV * 16) / 256, 256, 0, stream>>>(k_h, cost, sint, NKV);

  attn_kernel<<<512, 256, 0, stream>>>(q_h, k_h, Vt, o_h);

  // output projection
  cvt_f32_f16<<<16384, 256, 0, stream>>>(wo, wbuf, (HID * HID) / 4);
  gemm_h<1><<<dim3(32, 16), 256, 0, stream>>>(o_h, wbuf, d_out, S_LEN, HID, HID);
}

// Round 3
// 542.300 us; speedup vs baseline: 1.5635x; 1.1195x over previous
//
#include <hip/hip_runtime.h>
#include <hip/hip_bf16.h>

// MockLlamaAttention R3: B=1, S=2048, HIDDEN=4096, H=32, HKV=8, D=128, G=4.
// Changes vs R2: flash split-KV attention (2 splits -> 1024 blocks, 4/CU,
// fixes the 12.65%-occupancy latency wall), normalized f16 partials aliased
// onto the dead weight-cvt buffer, plus a combine kernel. GEMMs unchanged.
// Workspace usage: 75 MiB.

typedef _Float16 half4_t __attribute__((ext_vector_type(4)));
typedef _Float16 half8_t __attribute__((ext_vector_type(8)));
typedef float f32x4 __attribute__((ext_vector_type(4)));

#define S_LEN 2048
#define HID 4096
#define NH 32
#define NKV 8

__device__ __forceinline__ void gload_lds16(const void* g, void* l) {
  __builtin_amdgcn_global_load_lds((const __attribute__((address_space(1))) void*)g,
                                   (__attribute__((address_space(3))) void*)l, 16, 0, 0);
}

// ---------------- fp32 -> f16 convert (vectorized) ----------------
__global__ __launch_bounds__(256) void cvt_f32_f16(const float* __restrict__ src,
                                                   _Float16* __restrict__ dst, int n4) {
  int i = blockIdx.x * 256 + threadIdx.x;
  if (i >= n4) return;
  f32x4 v = *(const f32x4*)(src + (size_t)i * 4);
  half4_t h = {(_Float16)v[0], (_Float16)v[1], (_Float16)v[2], (_Float16)v[3]};
  *(half4_t*)(dst + (size_t)i * 4) = h;
}

// ---------------- RoPE cos/sin table: [2048][64] fp32 ----------------
__global__ __launch_bounds__(256) void rope_table_kernel(float* __restrict__ cost,
                                                         float* __restrict__ sint) {
  int i = blockIdx.x * 256 + threadIdx.x;
  int d = i & 63;
  int s = i >> 6;
  float inv = exp2f(-(float)d * (13.287712379549449f / 64.0f));
  float f = (float)s * inv;
  cost[i] = cosf(f);
  sint[i] = sinf(f);
}

// ---------------- RoPE apply (rotate_half), in place on f16 [S][heads*128] ----
__global__ __launch_bounds__(256) void rope_apply_kernel(_Float16* __restrict__ X,
                                                         const float* __restrict__ cost,
                                                         const float* __restrict__ sint,
                                                         int heads) {
  int idx = blockIdx.x * 256 + threadIdx.x;
  int g = idx & 15;
  int tmp = idx >> 4;
  int h = tmp % heads;
  int s = tmp / heads;
  int d0 = g * 4;
  size_t base = (size_t)s * (heads * 128) + h * 128 + d0;
  half4_t x1 = *(half4_t*)(X + base);
  half4_t x2 = *(half4_t*)(X + base + 64);
  const float* cp = cost + s * 64 + d0;
  const float* sp = sint + s * 64 + d0;
  half4_t y1, y2;
#pragma unroll
  for (int j = 0; j < 4; ++j) {
    float c = cp[j], sn = sp[j];
    float a = (float)x1[j], b = (float)x2[j];
    y1[j] = (_Float16)(a * c - b * sn);
    y2[j] = (_Float16)(b * c + a * sn);
  }
  *(half4_t*)(X + base) = y1;
  *(half4_t*)(X + base + 64) = y2;
}

// ---------------- GEMM (m97 structure): C[M,N] = A[M,K]f16 @ W[N,K]f16^T ------
template <int MODE>  // 0: f16 C, 1: f32 C
__global__ __launch_bounds__(256) void gemm_h(const _Float16* __restrict__ A,
                                              const _Float16* __restrict__ W,
                                              void* __restrict__ Cout,
                                              int M, int N, int K) {
  __shared__ __align__(16) _Float16 As[128 * 32];
  __shared__ __align__(16) _Float16 Bs[128 * 32];
  const int t = threadIdx.x, w = t >> 6, l = t & 63, lr = l & 15, lg = l >> 4;
  const int m0 = blockIdx.y * 128, n0 = blockIdx.x * 128;
  const int wm = (w >> 1) * 64, wn = (w & 1) * 64;
  const int srow = l >> 2, scol = (l & 3) * 8;
  f32x4 acc[4][4] = {};
  const _Float16* ap = A + (size_t)m0 * K + scol;
  const _Float16* bp = W + (size_t)n0 * K + scol;

  for (int kb = 0; kb < K; kb += 32) {
#pragma unroll
    for (int it = 0; it < 2; ++it) {
      const int ci = it * 4 + w;
      const int r = ci * 16 + srow;
      gload_lds16(ap + (size_t)r * K + kb, As + ci * 512);
      gload_lds16(bp + (size_t)r * K + kb, Bs + ci * 512);
    }
    __syncthreads();
    half8_t af[4], bf[4];
#pragma unroll
    for (int mi = 0; mi < 4; ++mi)
      af[mi] = *(const half8_t*)(As + (wm + mi * 16 + lr) * 32 + lg * 8);
#pragma unroll
    for (int ni = 0; ni < 4; ++ni)
      bf[ni] = *(const half8_t*)(Bs + (wn + ni * 16 + lr) * 32 + lg * 8);
#pragma unroll
    for (int mi = 0; mi < 4; ++mi)
#pragma unroll
      for (int ni = 0; ni < 4; ++ni)
        acc[mi][ni] = __builtin_amdgcn_mfma_f32_16x16x32_f16(af[mi], bf[ni], acc[mi][ni], 0, 0, 0);
    __syncthreads();
  }

#pragma unroll
  for (int mi = 0; mi < 4; ++mi) {
#pragma unroll
    for (int ni = 0; ni < 4; ++ni) {
      int row = m0 + wm + mi * 16 + lg * 4;
      int col = n0 + wn + ni * 16 + lr;
#pragma unroll
      for (int i = 0; i < 4; ++i) {
        if (MODE == 1)
          ((float*)Cout)[(size_t)(row + i) * N + col] = acc[mi][ni][i];
        else
          ((_Float16*)Cout)[(size_t)(row + i) * N + col] = (_Float16)acc[mi][ni][i];
      }
    }
  }
}

// ---------------- fused K/V projection; V written transposed -----------------
__global__ __launch_bounds__(256) void gemm_kv(const _Float16* __restrict__ A,
                                               const _Float16* __restrict__ Wk,
                                               const _Float16* __restrict__ Wv,
                                               _Float16* __restrict__ Ck,
                                               _Float16* __restrict__ Vt) {
  __shared__ __align__(16) _Float16 As[128 * 32];
  __shared__ __align__(16) _Float16 Bs[128 * 32];
  const int K = HID;
  const int t = threadIdx.x, w = t >> 6, l = t & 63, lr = l & 15, lg = l >> 4;
  const bool isv = blockIdx.x >= 8;
  const int m0 = blockIdx.y * 128, n0 = (blockIdx.x & 7) * 128;
  const _Float16* W = isv ? Wv : Wk;
  const int wm = (w >> 1) * 64, wn = (w & 1) * 64;
  const int srow = l >> 2, scol = (l & 3) * 8;
  f32x4 acc[4][4] = {};
  const _Float16* ap = A + (size_t)m0 * K + scol;
  const _Float16* bp = W + (size_t)n0 * K + scol;

  for (int kb = 0; kb < K; kb += 32) {
#pragma unroll
    for (int it = 0; it < 2; ++it) {
      const int ci = it * 4 + w;
      const int r = ci * 16 + srow;
      gload_lds16(ap + (size_t)r * K + kb, As + ci * 512);
      gload_lds16(bp + (size_t)r * K + kb, Bs + ci * 512);
    }
    __syncthreads();
    half8_t af[4], bf[4];
#pragma unroll
    for (int mi = 0; mi < 4; ++mi)
      af[mi] = *(const half8_t*)(As + (wm + mi * 16 + lr) * 32 + lg * 8);
#pragma unroll
    for (int ni = 0; ni < 4; ++ni)
      bf[ni] = *(const half8_t*)(Bs + (wn + ni * 16 + lr) * 32 + lg * 8);
#pragma unroll
    for (int mi = 0; mi < 4; ++mi)
#pragma unroll
      for (int ni = 0; ni < 4; ++ni)
        acc[mi][ni] = __builtin_amdgcn_mfma_f32_16x16x32_f16(af[mi], bf[ni], acc[mi][ni], 0, 0, 0);
    __syncthreads();
  }

#pragma unroll
  for (int mi = 0; mi < 4; ++mi) {
#pragma unroll
    for (int ni = 0; ni < 4; ++ni) {
      int row = m0 + wm + mi * 16 + lg * 4;
      int col = n0 + wn + ni * 16 + lr;
      if (!isv) {
#pragma unroll
        for (int i = 0; i < 4; ++i)
          Ck[(size_t)(row + i) * (NKV * 128) + col] = (_Float16)acc[mi][ni][i];
      } else {
        half4_t o;
#pragma unroll
        for (int i = 0; i < 4; ++i) o[i] = (_Float16)acc[mi][ni][i];
        *(half4_t*)(Vt + (size_t)col * S_LEN + row) = o;  // V^T[feat][seq]
      }
    }
  }
}

// ---------------- Flash attention v3: split-KV (causal, GQA) ----------------
// 1024 blocks: 16 per q-tile = 8 kv-heads x 2 KV-splits; heavy q-tiles first.
// Block = 4 waves = 4 q-heads of one kv group. Wave: 32 q rows (2 frags).
// Each split writes normalized f16 partial O + (m, den) per row; combined later.
__global__ __launch_bounds__(256) void attn_kernel(const _Float16* __restrict__ Q,
                                                   const _Float16* __restrict__ K,
                                                   const _Float16* __restrict__ Vt,
                                                   _Float16* __restrict__ Op,
                                                   float* __restrict__ Md) {
  const int bid = blockIdx.x;
  const int hk = bid & 7;                 // XCD-affine kv head
  const int split = (bid >> 3) & 1;
  const int qt = 63 - (bid >> 4);         // heaviest q-tiles dispatched first
  const int w = threadIdx.x >> 6;
  const int h = hk * 4 + w;
  const int l = threadIdx.x & 63;
  const int lr = l & 15;
  const int lg = l >> 4;
  const float scale = 0.08838834764831845f;  // 1/sqrt(128)
  const float LOG2E = 1.4426950408889634f;
  const float NEG = -1.0e30f;

  const int half_steps = qt + 1;          // ns = 2*(qt+1), equal halves
  const int kt0 = split * half_steps;
  const int kt1 = kt0 + half_steps;

  int sq[2];
  half8_t qf[2][4];
#pragma unroll
  for (int qc = 0; qc < 2; ++qc) {
    sq[qc] = qt * 32 + qc * 16 + lr;
#pragma unroll
    for (int c = 0; c < 4; ++c)
      qf[qc][c] = *(const half8_t*)(Q + (size_t)sq[qc] * HID + h * 128 + c * 32 + lg * 8);
  }
  f32x4 acc[8][2] = {};
  float m[2] = {NEG, NEG};
  float den[2] = {0.f, 0.f};

  for (int kt = kt0; kt < kt1; ++kt) {
    const int kr = kt * 16 + lr;
    half8_t kf[4];
#pragma unroll
    for (int c = 0; c < 4; ++c)
      kf[c] = *(const half8_t*)(K + (size_t)kr * (NKV * 128) + hk * 128 + c * 32 + lg * 8);
    f32x4 s0 = {0.f, 0.f, 0.f, 0.f}, s1 = {0.f, 0.f, 0.f, 0.f};
#pragma unroll
    for (int c = 0; c < 4; ++c) {
      s0 = __builtin_amdgcn_mfma_f32_16x16x32_f16(kf[c], qf[0][c], s0, 0, 0, 0);
      s1 = __builtin_amdgcn_mfma_f32_16x16x32_f16(kf[c], qf[1][c], s1, 0, 0, 0);
    }
    const int kbase = kt * 16 + lg * 4;
    float sc[2][4];
#pragma unroll
    for (int i = 0; i < 4; ++i) {
      sc[0][i] = s0[i] * scale;
      sc[1][i] = s1[i] * scale;
    }
    if (kt >= 2 * qt) {  // only the last two global steps can hit the causal edge
#pragma unroll
      for (int qc = 0; qc < 2; ++qc)
#pragma unroll
        for (int i = 0; i < 4; ++i)
          if (kbase + i > sq[qc]) sc[qc][i] = NEG;
    }
    half4_t pf[2];
#pragma unroll
    for (int qc = 0; qc < 2; ++qc) {
      float mx = fmaxf(fmaxf(sc[qc][0], sc[qc][1]), fmaxf(sc[qc][2], sc[qc][3]));
      mx = fmaxf(mx, __shfl_xor(mx, 16));
      mx = fmaxf(mx, __shfl_xor(mx, 32));
      if (!__all(mx - m[qc] <= 8.0f)) {  // defer-max (T13)
        float mn = fmaxf(m[qc], mx);
        float corr = exp2f((m[qc] - mn) * LOG2E);
        den[qc] *= corr;
#pragma unroll
        for (int dc = 0; dc < 8; ++dc)
#pragma unroll
          for (int i = 0; i < 4; ++i) acc[dc][qc][i] *= corr;
        m[qc] = mn;
      }
      float ps = 0.f, p[4];
#pragma unroll
      for (int i = 0; i < 4; ++i) {
        p[i] = exp2f((sc[qc][i] - m[qc]) * LOG2E);
        ps += p[i];
      }
      ps += __shfl_xor(ps, 16);
      ps += __shfl_xor(ps, 32);
      den[qc] += ps;
      pf[qc] = (half4_t){(_Float16)p[0], (_Float16)p[1], (_Float16)p[2], (_Float16)p[3]};
    }
#pragma unroll
    for (int dc = 0; dc < 8; ++dc) {
      half4_t vf = *(const half4_t*)(Vt + (size_t)(hk * 128 + dc * 16 + lr) * S_LEN + kt * 16 + lg * 4);
      acc[dc][0] = __builtin_amdgcn_mfma_f32_16x16x16f16(vf, pf[0], acc[dc][0], 0, 0, 0);
      acc[dc][1] = __builtin_amdgcn_mfma_f32_16x16x16f16(vf, pf[1], acc[dc][1], 0, 0, 0);
    }
  }

  _Float16* Os = Op + (size_t)split * S_LEN * HID;
#pragma unroll
  for (int qc = 0; qc < 2; ++qc) {
    float inv = den[qc] > 0.f ? 1.0f / den[qc] : 0.f;
#pragma unroll
    for (int dc = 0; dc < 8; ++dc) {
      half4_t o;
#pragma unroll
      for (int i = 0; i < 4; ++i) o[i] = (_Float16)(acc[dc][qc][i] * inv);
      *(half4_t*)(Os + (size_t)sq[qc] * HID + h * 128 + dc * 16 + lg * 4) = o;
    }
    if (lg == 0) {  // one lane per q-row writes (m, den)
      int mdix = ((split * S_LEN + sq[qc]) * NH + h) * 2;
      Md[mdix] = m[qc];
      Md[mdix + 1] = den[qc];
    }
  }
}

// ---------------- split-KV combine: O = (w0*O0 + w1*O1)/(w0+w1) --------------
__global__ __launch_bounds__(256) void attn_combine(const _Float16* __restrict__ Op,
                                                    const float* __restrict__ Md,
                                                    _Float16* __restrict__ O) {
  const float LOG2E = 1.4426950408889634f;
  int idx = blockIdx.x * 256 + threadIdx.x;  // 2048*32*16 = 1M threads
  int dd = (idx & 15) * 8;
  int h = (idx >> 4) & 31;
  int s = idx >> 9;
  int base = (s * NH + h) * 2;
  float m0 = Md[base], den0 = Md[base + 1];
  float m1 = Md[S_LEN * NH * 2 + base], den1 = Md[S_LEN * NH * 2 + base + 1];
  float M = fmaxf(m0, m1);
  float w0 = den0 * exp2f((m0 - M) * LOG2E);
  float w1 = den1 * exp2f((m1 - M) * LOG2E);
  float r = 1.0f / (w0 + w1);
  w0 *= r;
  w1 *= r;
  size_t off = (size_t)s * HID + h * 128 + dd;
  half8_t a = *(const half8_t*)(Op + off);
  half8_t b = *(const half8_t*)(Op + (size_t)S_LEN * HID + off);
  half8_t o;
#pragma unroll
  for (int j = 0; j < 8; ++j) o[j] = (_Float16)(w0 * (float)a[j] + w1 * (float)b[j]);
  *(half8_t*)(O + off) = o;
}

// ---------------- launcher ----------------
extern "C" void kernel_launch(void* const* d_in, const int* in_sizes, int n_in,
                              void* d_out, int out_size, void* d_ws, size_t ws_size,
                              hipStream_t stream) {
  (void)in_sizes; (void)n_in; (void)out_size; (void)ws_size;
  const float* hs = (const float*)d_in[0];
  const float* wq = (const float*)d_in[1];
  const float* wk = (const float*)d_in[2];
  const float* wv = (const float*)d_in[3];
  const float* wo = (const float*)d_in[4];

  char* ws = (char*)d_ws;
  _Float16* hs_h = (_Float16*)(ws);                       // 16 MiB
  _Float16* q_h  = (_Float16*)(ws + (16u << 20));         // 16 MiB
  _Float16* k_h  = (_Float16*)(ws + (32u << 20));         // 4 MiB
  _Float16* Vt   = (_Float16*)(ws + (36u << 20));         // 4 MiB [1024][2048]
  float* cost    = (float*)(ws + (40u << 20));            // 512 KiB
  float* sint    = (float*)(ws + (40u << 20) + (512u << 10));
  _Float16* wbuf = (_Float16*)(ws + (41u << 20));         // 32 MiB f16 weights
  _Float16* wbuf2 = wbuf + (8u << 20) / 2;
  _Float16* Op   = wbuf;                                  // alias: attention partials
  float* Md      = (float*)(ws + (73u << 20));            // 2 MiB (m, den)
  _Float16* o_h  = hs_h;                                  // alias: hs dead after KV proj

  cvt_f32_f16<<<8192, 256, 0, stream>>>(hs, hs_h, (S_LEN * HID) / 4);
  rope_table_kernel<<<(S_LEN * 64) / 256, 256, 0, stream>>>(cost, sint);

  // Q projection
  cvt_f32_f16<<<16384, 256, 0, stream>>>(wq, wbuf, (HID * HID) / 4);
  gemm_h<0><<<dim3(32, 16), 256, 0, stream>>>(hs_h, wbuf, q_h, S_LEN, HID, HID);

  // K + V projections (V transposed on store)
  cvt_f32_f16<<<4096, 256, 0, stream>>>(wk, wbuf, (NKV * 128 * HID) / 4);
  cvt_f32_f16<<<4096, 256, 0, stream>>>(wv, wbuf2, (NKV * 128 * HID) / 4);
  gemm_kv<<<dim3(16, 16), 256, 0, stream>>>(hs_h, wbuf, wbuf2, k_h, Vt);

  rope_apply_kernel<<<(S_LEN * NH * 16) / 256, 256, 0, stream>>>(q_h, cost, sint, NH);
  rope_apply_kernel<<<(S_LEN * NKV * 16) / 256, 256, 0, stream>>>(k_h, cost, sint, NKV);

  // attention: 2-way split-KV into normalized partials (aliased on wbuf), combine
  attn_kernel<<<1024, 256, 0, stream>>>(q_h, k_h, Vt, Op, Md);
  attn_combine<<<4096, 256, 0, stream>>>(Op, Md, o_h);

  // output projection
  cvt_f32_f16<<<16384, 256, 0, stream>>>(wo, wbuf, (HID * HID) / 4);
  gemm_h<1><<<dim3(32, 16), 256, 0, stream>>>(o_h, wbuf, d_out, S_LEN, HID, HID);
}

// Round 4
// 447.893 us; speedup vs baseline: 1.8931x; 1.2108x over previous
//
#include <hip/hip_runtime.h>
#include <hip/hip_bf16.h>

// MockLlamaAttention R4: B=1, S=2048, HIDDEN=4096, H=32, HKV=8, D=128, G=4.
// Changes vs R3: coalesced attention operand layouts.
//   K2 [NKV][S/16][d/8][16k][8d]  (QK B-frag load = contiguous 1KB/wave)
//   V2 [NKV][S/16][128d][16k]     (PV A-frag load = contiguous 512B/wave)
// K2 built by the K-RoPE pass (into dead hs_h region); V2 written by the
// V-projection epilogue. Attention math identical to R3 (split-KV x2).
// Workspace usage: 75 MiB.

typedef _Float16 half4_t __attribute__((ext_vector_type(4)));
typedef _Float16 half8_t __attribute__((ext_vector_type(8)));
typedef float f32x4 __attribute__((ext_vector_type(4)));

#define S_LEN 2048
#define HID 4096
#define NH 32
#define NKV 8

__device__ __forceinline__ void gload_lds16(const void* g, void* l) {
  __builtin_amdgcn_global_load_lds((const __attribute__((address_space(1))) void*)g,
                                   (__attribute__((address_space(3))) void*)l, 16, 0, 0);
}

// ---------------- fp32 -> f16 convert (vectorized) ----------------
__global__ __launch_bounds__(256) void cvt_f32_f16(const float* __restrict__ src,
                                                   _Float16* __restrict__ dst, int n4) {
  int i = blockIdx.x * 256 + threadIdx.x;
  if (i >= n4) return;
  f32x4 v = *(const f32x4*)(src + (size_t)i * 4);
  half4_t h = {(_Float16)v[0], (_Float16)v[1], (_Float16)v[2], (_Float16)v[3]};
  *(half4_t*)(dst + (size_t)i * 4) = h;
}

// ---------------- RoPE cos/sin table: [2048][64] fp32 ----------------
__global__ __launch_bounds__(256) void rope_table_kernel(float* __restrict__ cost,
                                                         float* __restrict__ sint) {
  int i = blockIdx.x * 256 + threadIdx.x;
  int d = i & 63;
  int s = i >> 6;
  float inv = exp2f(-(float)d * (13.287712379549449f / 64.0f));
  float f = (float)s * inv;
  cost[i] = cosf(f);
  sint[i] = sinf(f);
}

// ---------------- RoPE apply for Q (in place, [S][NH*128]) ----------------
__global__ __launch_bounds__(256) void rope_apply_q(_Float16* __restrict__ X,
                                                    const float* __restrict__ cost,
                                                    const float* __restrict__ sint) {
  int idx = blockIdx.x * 256 + threadIdx.x;
  int g = idx & 15;
  int tmp = idx >> 4;
  int h = tmp % NH;
  int s = tmp / NH;
  int d0 = g * 4;
  size_t base = (size_t)s * HID + h * 128 + d0;
  half4_t x1 = *(half4_t*)(X + base);
  half4_t x2 = *(half4_t*)(X + base + 64);
  const float* cp = cost + s * 64 + d0;
  const float* sp = sint + s * 64 + d0;
  half4_t y1, y2;
#pragma unroll
  for (int j = 0; j < 4; ++j) {
    float c = cp[j], sn = sp[j];
    float a = (float)x1[j], b = (float)x2[j];
    y1[j] = (_Float16)(a * c - b * sn);
    y2[j] = (_Float16)(b * c + a * sn);
  }
  *(half4_t*)(X + base) = y1;
  *(half4_t*)(X + base + 64) = y2;
}

// ------- RoPE apply for K: k_h [S][NKV*128] -> K2 tiled [NKV][S/16][d/8][16][8]
__global__ __launch_bounds__(256) void rope_apply_k2(const _Float16* __restrict__ Kin,
                                                     const float* __restrict__ cost,
                                                     const float* __restrict__ sint,
                                                     _Float16* __restrict__ K2) {
  int idx = blockIdx.x * 256 + threadIdx.x;  // S*NKV*16
  int g = idx & 15;
  int tmp = idx >> 4;
  int h = tmp % NKV;
  int s = tmp / NKV;
  int d0 = g * 4;
  size_t base = (size_t)s * (NKV * 128) + h * 128 + d0;
  half4_t x1 = *(const half4_t*)(Kin + base);
  half4_t x2 = *(const half4_t*)(Kin + base + 64);
  const float* cp = cost + s * 64 + d0;
  const float* sp = sint + s * 64 + d0;
  half4_t y1, y2;
#pragma unroll
  for (int j = 0; j < 4; ++j) {
    float c = cp[j], sn = sp[j];
    float a = (float)x1[j], b = (float)x2[j];
    y1[j] = (_Float16)(a * c - b * sn);
    y2[j] = (_Float16)(b * c + a * sn);
  }
  // K2 elem = h*(S*128) + (s>>4)*2048 + (d>>3)*128 + (s&15)*8 + (d&7)
  size_t tb = (size_t)h * (S_LEN * 128) + (size_t)(s >> 4) * 2048 + (size_t)(s & 15) * 8;
  int d1 = d0, d2 = d0 + 64;
  *(half4_t*)(K2 + tb + (d1 >> 3) * 128 + (d1 & 7)) = y1;
  *(half4_t*)(K2 + tb + (d2 >> 3) * 128 + (d2 & 7)) = y2;
}

// ---------------- GEMM (m97 structure): C[M,N] = A[M,K]f16 @ W[N,K]f16^T ------
template <int MODE>  // 0: f16 C, 1: f32 C
__global__ __launch_bounds__(256) void gemm_h(const _Float16* __restrict__ A,
                                              const _Float16* __restrict__ W,
                                              void* __restrict__ Cout,
                                              int M, int N, int K) {
  __shared__ __align__(16) _Float16 As[128 * 32];
  __shared__ __align__(16) _Float16 Bs[128 * 32];
  const int t = threadIdx.x, w = t >> 6, l = t & 63, lr = l & 15, lg = l >> 4;
  const int m0 = blockIdx.y * 128, n0 = blockIdx.x * 128;
  const int wm = (w >> 1) * 64, wn = (w & 1) * 64;
  const int srow = l >> 2, scol = (l & 3) * 8;
  f32x4 acc[4][4] = {};
  const _Float16* ap = A + (size_t)m0 * K + scol;
  const _Float16* bp = W + (size_t)n0 * K + scol;

  for (int kb = 0; kb < K; kb += 32) {
#pragma unroll
    for (int it = 0; it < 2; ++it) {
      const int ci = it * 4 + w;
      const int r = ci * 16 + srow;
      gload_lds16(ap + (size_t)r * K + kb, As + ci * 512);
      gload_lds16(bp + (size_t)r * K + kb, Bs + ci * 512);
    }
    __syncthreads();
    half8_t af[4], bf[4];
#pragma unroll
    for (int mi = 0; mi < 4; ++mi)
      af[mi] = *(const half8_t*)(As + (wm + mi * 16 + lr) * 32 + lg * 8);
#pragma unroll
    for (int ni = 0; ni < 4; ++ni)
      bf[ni] = *(const half8_t*)(Bs + (wn + ni * 16 + lr) * 32 + lg * 8);
#pragma unroll
    for (int mi = 0; mi < 4; ++mi)
#pragma unroll
      for (int ni = 0; ni < 4; ++ni)
        acc[mi][ni] = __builtin_amdgcn_mfma_f32_16x16x32_f16(af[mi], bf[ni], acc[mi][ni], 0, 0, 0);
    __syncthreads();
  }

#pragma unroll
  for (int mi = 0; mi < 4; ++mi) {
#pragma unroll
    for (int ni = 0; ni < 4; ++ni) {
      int row = m0 + wm + mi * 16 + lg * 4;
      int col = n0 + wn + ni * 16 + lr;
#pragma unroll
      for (int i = 0; i < 4; ++i) {
        if (MODE == 1)
          ((float*)Cout)[(size_t)(row + i) * N + col] = acc[mi][ni][i];
        else
          ((_Float16*)Cout)[(size_t)(row + i) * N + col] = (_Float16)acc[mi][ni][i];
      }
    }
  }
}

// ------- fused K/V projection; K natural [S][1024], V in V2 tiled layout -----
__global__ __launch_bounds__(256) void gemm_kv(const _Float16* __restrict__ A,
                                               const _Float16* __restrict__ Wk,
                                               const _Float16* __restrict__ Wv,
                                               _Float16* __restrict__ Ck,
                                               _Float16* __restrict__ V2) {
  __shared__ __align__(16) _Float16 As[128 * 32];
  __shared__ __align__(16) _Float16 Bs[128 * 32];
  const int K = HID;
  const int t = threadIdx.x, w = t >> 6, l = t & 63, lr = l & 15, lg = l >> 4;
  const bool isv = blockIdx.x >= 8;
  const int m0 = blockIdx.y * 128, n0 = (blockIdx.x & 7) * 128;
  const _Float16* W = isv ? Wv : Wk;
  const int wm = (w >> 1) * 64, wn = (w & 1) * 64;
  const int srow = l >> 2, scol = (l & 3) * 8;
  f32x4 acc[4][4] = {};
  const _Float16* ap = A + (size_t)m0 * K + scol;
  const _Float16* bp = W + (size_t)n0 * K + scol;

  for (int kb = 0; kb < K; kb += 32) {
#pragma unroll
    for (int it = 0; it < 2; ++it) {
      const int ci = it * 4 + w;
      const int r = ci * 16 + srow;
      gload_lds16(ap + (size_t)r * K + kb, As + ci * 512);
      gload_lds16(bp + (size_t)r * K + kb, Bs + ci * 512);
    }
    __syncthreads();
    half8_t af[4], bf[4];
#pragma unroll
    for (int mi = 0; mi < 4; ++mi)
      af[mi] = *(const half8_t*)(As + (wm + mi * 16 + lr) * 32 + lg * 8);
#pragma unroll
    for (int ni = 0; ni < 4; ++ni)
      bf[ni] = *(const half8_t*)(Bs + (wn + ni * 16 + lr) * 32 + lg * 8);
#pragma unroll
    for (int mi = 0; mi < 4; ++mi)
#pragma unroll
      for (int ni = 0; ni < 4; ++ni)
        acc[mi][ni] = __builtin_amdgcn_mfma_f32_16x16x32_f16(af[mi], bf[ni], acc[mi][ni], 0, 0, 0);
    __syncthreads();
  }

#pragma unroll
  for (int mi = 0; mi < 4; ++mi) {
#pragma unroll
    for (int ni = 0; ni < 4; ++ni) {
      int row = m0 + wm + mi * 16 + lg * 4;  // seq
      int col = n0 + wn + ni * 16 + lr;      // feature 0..1023
      if (!isv) {
#pragma unroll
        for (int i = 0; i < 4; ++i)
          Ck[(size_t)(row + i) * (NKV * 128) + col] = (_Float16)acc[mi][ni][i];
      } else {
        half4_t o;
#pragma unroll
        for (int i = 0; i < 4; ++i) o[i] = (_Float16)acc[mi][ni][i];
        // V2 elem = (col>>7)*(S*128) + (row>>4)*2048 + (col&127)*16 + (row&15)
        *(half4_t*)(V2 + (size_t)(col >> 7) * (S_LEN * 128) + (size_t)(row >> 4) * 2048 +
                    (size_t)(col & 127) * 16 + (row & 15)) = o;
      }
    }
  }
}

// ---------------- Flash attention v4: split-KV, tiled K2/V2 ----------------
__global__ __launch_bounds__(256) void attn_kernel(const _Float16* __restrict__ Q,
                                                   const _Float16* __restrict__ K2,
                                                   const _Float16* __restrict__ V2,
                                                   _Float16* __restrict__ Op,
                                                   float* __restrict__ Md) {
  const int bid = blockIdx.x;
  const int hk = bid & 7;                 // XCD-affine kv head
  const int split = (bid >> 3) & 1;
  const int qt = 63 - (bid >> 4);         // heaviest q-tiles first
  const int w = threadIdx.x >> 6;
  const int h = hk * 4 + w;
  const int l = threadIdx.x & 63;
  const int lr = l & 15;
  const int lg = l >> 4;
  const float scale = 0.08838834764831845f;  // 1/sqrt(128)
  const float LOG2E = 1.4426950408889634f;
  const float NEG = -1.0e30f;

  const int half_steps = qt + 1;
  const int kt0 = split * half_steps;
  const int kt1 = kt0 + half_steps;

  int sq[2];
  half8_t qf[2][4];
#pragma unroll
  for (int qc = 0; qc < 2; ++qc) {
    sq[qc] = qt * 32 + qc * 16 + lr;
#pragma unroll
    for (int c = 0; c < 4; ++c)
      qf[qc][c] = *(const half8_t*)(Q + (size_t)sq[qc] * HID + h * 128 + c * 32 + lg * 8);
  }
  const _Float16* Kb = K2 + (size_t)hk * (S_LEN * 128);
  const _Float16* Vb = V2 + (size_t)hk * (S_LEN * 128);

  f32x4 acc[8][2] = {};
  float m[2] = {NEG, NEG};
  float den[2] = {0.f, 0.f};

  for (int kt = kt0; kt < kt1; ++kt) {
    half8_t kf[4];
#pragma unroll
    for (int c = 0; c < 4; ++c)
      kf[c] = *(const half8_t*)(Kb + (size_t)kt * 2048 + (c * 4 + lg) * 128 + lr * 8);
    f32x4 s0 = {0.f, 0.f, 0.f, 0.f}, s1 = {0.f, 0.f, 0.f, 0.f};
#pragma unroll
    for (int c = 0; c < 4; ++c) {
      s0 = __builtin_amdgcn_mfma_f32_16x16x32_f16(kf[c], qf[0][c], s0, 0, 0, 0);
      s1 = __builtin_amdgcn_mfma_f32_16x16x32_f16(kf[c], qf[1][c], s1, 0, 0, 0);
    }
    const int kbase = kt * 16 + lg * 4;
    float sc[2][4];
#pragma unroll
    for (int i = 0; i < 4; ++i) {
      sc[0][i] = s0[i] * scale;
      sc[1][i] = s1[i] * scale;
    }
    if (kt >= 2 * qt) {
#pragma unroll
      for (int qc = 0; qc < 2; ++qc)
#pragma unroll
        for (int i = 0; i < 4; ++i)
          if (kbase + i > sq[qc]) sc[qc][i] = NEG;
    }
    half4_t pf[2];
#pragma unroll
    for (int qc = 0; qc < 2; ++qc) {
      float mx = fmaxf(fmaxf(sc[qc][0], sc[qc][1]), fmaxf(sc[qc][2], sc[qc][3]));
      mx = fmaxf(mx, __shfl_xor(mx, 16));
      mx = fmaxf(mx, __shfl_xor(mx, 32));
      if (!__all(mx - m[qc] <= 8.0f)) {  // defer-max (T13)
        float mn = fmaxf(m[qc], mx);
        float corr = exp2f((m[qc] - mn) * LOG2E);
        den[qc] *= corr;
#pragma unroll
        for (int dc = 0; dc < 8; ++dc)
#pragma unroll
          for (int i = 0; i < 4; ++i) acc[dc][qc][i] *= corr;
        m[qc] = mn;
      }
      float ps = 0.f, p[4];
#pragma unroll
      for (int i = 0; i < 4; ++i) {
        p[i] = exp2f((sc[qc][i] - m[qc]) * LOG2E);
        ps += p[i];
      }
      ps += __shfl_xor(ps, 16);
      ps += __shfl_xor(ps, 32);
      den[qc] += ps;
      pf[qc] = (half4_t){(_Float16)p[0], (_Float16)p[1], (_Float16)p[2], (_Float16)p[3]};
    }
#pragma unroll
    for (int dc = 0; dc < 8; ++dc) {
      half4_t vf = *(const half4_t*)(Vb + (size_t)kt * 2048 + (dc * 16 + lr) * 16 + lg * 4);
      acc[dc][0] = __builtin_amdgcn_mfma_f32_16x16x16f16(vf, pf[0], acc[dc][0], 0, 0, 0);
      acc[dc][1] = __builtin_amdgcn_mfma_f32_16x16x16f16(vf, pf[1], acc[dc][1], 0, 0, 0);
    }
  }

  _Float16* Os = Op + (size_t)split * S_LEN * HID;
#pragma unroll
  for (int qc = 0; qc < 2; ++qc) {
    float inv = den[qc] > 0.f ? 1.0f / den[qc] : 0.f;
#pragma unroll
    for (int dc = 0; dc < 8; ++dc) {
      half4_t o;
#pragma unroll
      for (int i = 0; i < 4; ++i) o[i] = (_Float16)(acc[dc][qc][i] * inv);
      *(half4_t*)(Os + (size_t)sq[qc] * HID + h * 128 + dc * 16 + lg * 4) = o;
    }
    if (lg == 0) {
      int mdix = ((split * S_LEN + sq[qc]) * NH + h) * 2;
      Md[mdix] = m[qc];
      Md[mdix + 1] = den[qc];
    }
  }
}

// ---------------- split-KV combine: O = (w0*O0 + w1*O1)/(w0+w1) --------------
__global__ __launch_bounds__(256) void attn_combine(const _Float16* __restrict__ Op,
                                                    const float* __restrict__ Md,
                                                    _Float16* __restrict__ O) {
  const float LOG2E = 1.4426950408889634f;
  int idx = blockIdx.x * 256 + threadIdx.x;
  int dd = (idx & 15) * 8;
  int h = (idx >> 4) & 31;
  int s = idx >> 9;
  int base = (s * NH + h) * 2;
  float m0 = Md[base], den0 = Md[base + 1];
  float m1 = Md[S_LEN * NH * 2 + base], den1 = Md[S_LEN * NH * 2 + base + 1];
  float M = fmaxf(m0, m1);
  float w0 = den0 * exp2f((m0 - M) * LOG2E);
  float w1 = den1 * exp2f((m1 - M) * LOG2E);
  float r = 1.0f / (w0 + w1);
  w0 *= r;
  w1 *= r;
  size_t off = (size_t)s * HID + h * 128 + dd;
  half8_t a = *(const half8_t*)(Op + off);
  half8_t b = *(const half8_t*)(Op + (size_t)S_LEN * HID + off);
  half8_t o;
#pragma unroll
  for (int j = 0; j < 8; ++j) o[j] = (_Float16)(w0 * (float)a[j] + w1 * (float)b[j]);
  *(half8_t*)(O + off) = o;
}

// ---------------- launcher ----------------
extern "C" void kernel_launch(void* const* d_in, const int* in_sizes, int n_in,
                              void* d_out, int out_size, void* d_ws, size_t ws_size,
                              hipStream_t stream) {
  (void)in_sizes; (void)n_in; (void)out_size; (void)ws_size;
  const float* hs = (const float*)d_in[0];
  const float* wq = (const float*)d_in[1];
  const float* wk = (const float*)d_in[2];
  const float* wv = (const float*)d_in[3];
  const float* wo = (const float*)d_in[4];

  char* ws = (char*)d_ws;
  _Float16* hs_h = (_Float16*)(ws);                       // 16 MiB [0,16M)
  _Float16* K2   = hs_h;                                  // alias [0,4M): hs dead after gemm_kv
  _Float16* q_h  = (_Float16*)(ws + (16u << 20));         // 16 MiB
  _Float16* k_h  = (_Float16*)(ws + (32u << 20));         // 4 MiB (pre-rope K)
  _Float16* V2   = (_Float16*)(ws + (36u << 20));         // 4 MiB tiled V
  float* cost    = (float*)(ws + (40u << 20));            // 512 KiB
  float* sint    = (float*)(ws + (40u << 20) + (512u << 10));
  _Float16* wbuf = (_Float16*)(ws + (41u << 20));         // 32 MiB f16 weights
  _Float16* wbuf2 = wbuf + (8u << 20) / 2;
  _Float16* Op   = wbuf;                                  // alias: attention partials
  float* Md      = (float*)(ws + (73u << 20));            // 2 MiB (m, den)
  _Float16* o_h  = hs_h;                                  // combine output (K2 dead by then)

  cvt_f32_f16<<<8192, 256, 0, stream>>>(hs, hs_h, (S_LEN * HID) / 4);
  rope_table_kernel<<<(S_LEN * 64) / 256, 256, 0, stream>>>(cost, sint);

  // Q projection
  cvt_f32_f16<<<16384, 256, 0, stream>>>(wq, wbuf, (HID * HID) / 4);
  gemm_h<0><<<dim3(32, 16), 256, 0, stream>>>(hs_h, wbuf, q_h, S_LEN, HID, HID);

  // K + V projections (V written in V2 tiled layout)
  cvt_f32_f16<<<4096, 256, 0, stream>>>(wk, wbuf, (NKV * 128 * HID) / 4);
  cvt_f32_f16<<<4096, 256, 0, stream>>>(wv, wbuf2, (NKV * 128 * HID) / 4);
  gemm_kv<<<dim3(16, 16), 256, 0, stream>>>(hs_h, wbuf, wbuf2, k_h, V2);

  rope_apply_q<<<(S_LEN * NH * 16) / 256, 256, 0, stream>>>(q_h, cost, sint);
  rope_apply_k2<<<(S_LEN * NKV * 16) / 256, 256, 0, stream>>>(k_h, cost, sint, K2);

  // attention: 2-way split-KV into normalized partials, then combine
  attn_kernel<<<1024, 256, 0, stream>>>(q_h, K2, V2, Op, Md);
  attn_combine<<<4096, 256, 0, stream>>>(Op, Md, o_h);

  // output projection
  cvt_f32_f16<<<16384, 256, 0, stream>>>(wo, wbuf, (HID * HID) / 4);
  gemm_h<1><<<dim3(32, 16), 256, 0, stream>>>(o_h, wbuf, d_out, S_LEN, HID, HID);
}

// Round 5
// 402.080 us; speedup vs baseline: 2.1088x; 1.1139x over previous
//
#include <hip/hip_runtime.h>
#include <hip/hip_bf16.h>

// MockLlamaAttention R5: B=1, S=2048, HIDDEN=4096, H=32, HKV=8, D=128, G=4.
// Changes vs R4 (GEMMs only; attention untouched):
//   - T3-min double-buffered prefetch K-loop (stage next tile BEFORE compute,
//     ONE barrier per K-step; vmcnt(0) drain lands after compute).
//   - merged QKV projection (N=6144, 768 blocks = 3/CU) with per-block weight
//     select; K written directly in K2-tiled layout (k_h eliminated, RoPE
//     in-place on K2); V in V2-tiled layout. ws>=90MiB guarded, else 2-launch.
//   - bijective XCD swizzle on GEMM blocks (contiguous tile-rows per XCD).
// Workspace: merged 89 MiB / fallback 75 MiB.

typedef _Float16 half4_t __attribute__((ext_vector_type(4)));
typedef _Float16 half8_t __attribute__((ext_vector_type(8)));
typedef float f32x4 __attribute__((ext_vector_type(4)));

#define S_LEN 2048
#define HID 4096
#define NH 32
#define NKV 8

__device__ __forceinline__ void gload_lds16(const void* g, void* l) {
  __builtin_amdgcn_global_load_lds((const __attribute__((address_space(1))) void*)g,
                                   (__attribute__((address_space(3))) void*)l, 16, 0, 0);
}

// ---------------- fp32 -> f16 convert (vectorized) ----------------
__global__ __launch_bounds__(256) void cvt_f32_f16(const float* __restrict__ src,
                                                   _Float16* __restrict__ dst, int n4) {
  int i = blockIdx.x * 256 + threadIdx.x;
  if (i >= n4) return;
  f32x4 v = *(const f32x4*)(src + (size_t)i * 4);
  half4_t h = {(_Float16)v[0], (_Float16)v[1], (_Float16)v[2], (_Float16)v[3]};
  *(half4_t*)(dst + (size_t)i * 4) = h;
}

// ---------------- RoPE cos/sin table: [2048][64] fp32 ----------------
__global__ __launch_bounds__(256) void rope_table_kernel(float* __restrict__ cost,
                                                         float* __restrict__ sint) {
  int i = blockIdx.x * 256 + threadIdx.x;
  int d = i & 63;
  int s = i >> 6;
  float inv = exp2f(-(float)d * (13.287712379549449f / 64.0f));
  float f = (float)s * inv;
  cost[i] = cosf(f);
  sint[i] = sinf(f);
}

// ---------------- RoPE apply for Q (in place, [S][NH*128]) ----------------
__global__ __launch_bounds__(256) void rope_apply_q(_Float16* __restrict__ X,
                                                    const float* __restrict__ cost,
                                                    const float* __restrict__ sint) {
  int idx = blockIdx.x * 256 + threadIdx.x;
  int g = idx & 15;
  int tmp = idx >> 4;
  int h = tmp % NH;
  int s = tmp / NH;
  int d0 = g * 4;
  size_t base = (size_t)s * HID + h * 128 + d0;
  half4_t x1 = *(half4_t*)(X + base);
  half4_t x2 = *(half4_t*)(X + base + 64);
  const float* cp = cost + s * 64 + d0;
  const float* sp = sint + s * 64 + d0;
  half4_t y1, y2;
#pragma unroll
  for (int j = 0; j < 4; ++j) {
    float c = cp[j], sn = sp[j];
    float a = (float)x1[j], b = (float)x2[j];
    y1[j] = (_Float16)(a * c - b * sn);
    y2[j] = (_Float16)(b * c + a * sn);
  }
  *(half4_t*)(X + base) = y1;
  *(half4_t*)(X + base + 64) = y2;
}

// ------- RoPE apply for K, in place on tiled K2 [NKV][S/16][d/8][16s][8d] ----
__global__ __launch_bounds__(256) void rope_k2_inplace(_Float16* __restrict__ K2,
                                                       const float* __restrict__ cost,
                                                       const float* __restrict__ sint) {
  int idx = blockIdx.x * 256 + threadIdx.x;  // S*NKV*16
  int g = idx & 15;
  int tmp = idx >> 4;
  int h = tmp % NKV;
  int s = tmp / NKV;
  int d0 = g * 4;
  size_t tb = (size_t)h * (S_LEN * 128) + (size_t)(s >> 4) * 2048 + (size_t)(s & 15) * 8;
  size_t a1 = tb + (size_t)(d0 >> 3) * 128 + (d0 & 7);
  size_t a2 = a1 + 1024;  // d0+64: unit +8 -> +1024 halfs
  half4_t x1 = *(half4_t*)(K2 + a1);
  half4_t x2 = *(half4_t*)(K2 + a2);
  const float* cp = cost + s * 64 + d0;
  const float* sp = sint + s * 64 + d0;
  half4_t y1, y2;
#pragma unroll
  for (int j = 0; j < 4; ++j) {
    float c = cp[j], sn = sp[j];
    float a = (float)x1[j], b = (float)x2[j];
    y1[j] = (_Float16)(a * c - b * sn);
    y2[j] = (_Float16)(b * c + a * sn);
  }
  *(half4_t*)(K2 + a1) = y1;
  *(half4_t*)(K2 + a2) = y2;
}

// ---------------- GEMM v5: dbuf prefetch + XCD swizzle, K=4096 ----------------
// MODE 0: QKV epilogue (bx<32 -> q_h, 32..39 -> K2 tiled, 40..47 -> V2 tiled)
// MODE 1: f32 C [2048][4096] (O-projection)
template <int MODE>
__global__ __launch_bounds__(256) void gemm5(const _Float16* __restrict__ A,
                                             const _Float16* __restrict__ W0,
                                             const _Float16* __restrict__ W1,
                                             const _Float16* __restrict__ W2,
                                             void* __restrict__ out,
                                             _Float16* __restrict__ K2,
                                             _Float16* __restrict__ V2, int bxoff) {
  __shared__ __align__(16) _Float16 As[2][128 * 32];
  __shared__ __align__(16) _Float16 Bs[2][128 * 32];
  const int t = threadIdx.x, w = t >> 6, l = t & 63, lr = l & 15, lg = l >> 4;
  // bijective XCD swizzle: XCD k owns a contiguous tile-row chunk
  const int nwg = gridDim.x * gridDim.y;
  const int flat = blockIdx.y * gridDim.x + blockIdx.x;
  const int rm = (flat & 7) * (nwg >> 3) + (flat >> 3);
  const int bx = rm % gridDim.x + bxoff;
  const int by = rm / gridDim.x;
  const int m0 = by * 128;
  const _Float16* Wsel;
  int col0, sel;
  if (MODE == 1) {
    Wsel = W0; col0 = bx * 128; sel = 0;
  } else {
    if (bx < 32)      { Wsel = W0; col0 = bx * 128; sel = 0; }
    else if (bx < 40) { Wsel = W1; col0 = (bx - 32) * 128; sel = 1; }
    else              { Wsel = W2; col0 = (bx - 40) * 128; sel = 2; }
  }
  const int wm = (w >> 1) * 64, wn = (w & 1) * 64;
  const int srow = l >> 2, scol = (l & 3) * 8;
  const _Float16* ap = A + (size_t)m0 * 4096 + scol;
  const _Float16* bp = Wsel + (size_t)col0 * 4096 + scol;
  f32x4 acc[4][4] = {};

#define STAGE5(as_, bs_, kb_)                                     \
  _Pragma("unroll") for (int it = 0; it < 2; ++it) {              \
    const int ci = it * 4 + w;                                    \
    const int r = ci * 16 + srow;                                 \
    gload_lds16(ap + (size_t)r * 4096 + (kb_), (as_) + ci * 512); \
    gload_lds16(bp + (size_t)r * 4096 + (kb_), (bs_) + ci * 512); \
  }

  STAGE5(As[0], Bs[0], 0)
  __syncthreads();
  int cur = 0;
  for (int kb = 0; kb < 4096; kb += 32) {
    if (kb + 32 < 4096) {  // prefetch next tile BEFORE compute
      STAGE5(As[cur ^ 1], Bs[cur ^ 1], kb + 32)
    }
    half8_t af[4], bf[4];
#pragma unroll
    for (int mi = 0; mi < 4; ++mi)
      af[mi] = *(const half8_t*)(As[cur] + (wm + mi * 16 + lr) * 32 + lg * 8);
#pragma unroll
    for (int ni = 0; ni < 4; ++ni)
      bf[ni] = *(const half8_t*)(Bs[cur] + (wn + ni * 16 + lr) * 32 + lg * 8);
#pragma unroll
    for (int mi = 0; mi < 4; ++mi)
#pragma unroll
      for (int ni = 0; ni < 4; ++ni)
        acc[mi][ni] = __builtin_amdgcn_mfma_f32_16x16x32_f16(af[mi], bf[ni], acc[mi][ni], 0, 0, 0);
    __syncthreads();  // vmcnt(0) drain lands here, AFTER compute
    cur ^= 1;
  }
#undef STAGE5

#pragma unroll
  for (int mi = 0; mi < 4; ++mi) {
#pragma unroll
    for (int ni = 0; ni < 4; ++ni) {
      const int row = m0 + wm + mi * 16 + lg * 4;
      const int col = col0 + wn + ni * 16 + lr;
      if (MODE == 1) {
#pragma unroll
        for (int i = 0; i < 4; ++i)
          ((float*)out)[(size_t)(row + i) * 4096 + col] = acc[mi][ni][i];
      } else if (sel == 0) {
#pragma unroll
        for (int i = 0; i < 4; ++i)
          ((_Float16*)out)[(size_t)(row + i) * 4096 + col] = (_Float16)acc[mi][ni][i];
      } else if (sel == 1) {  // K2 tiled [NKV][S/16][d/8][16s][8d]
        const int h = col >> 7, d = col & 127;
        const size_t kb2 = (size_t)h * (S_LEN * 128) + (size_t)(row >> 4) * 2048 +
                           (size_t)(d >> 3) * 128 + (d & 7);
#pragma unroll
        for (int i = 0; i < 4; ++i)
          K2[kb2 + ((row + i) & 15) * 8] = (_Float16)acc[mi][ni][i];
      } else {  // V2 tiled [NKV][S/16][128d][16s]
        half4_t o;
#pragma unroll
        for (int i = 0; i < 4; ++i) o[i] = (_Float16)acc[mi][ni][i];
        *(half4_t*)(V2 + (size_t)(col >> 7) * (S_LEN * 128) + (size_t)(row >> 4) * 2048 +
                    (size_t)(col & 127) * 16 + (row & 15)) = o;
      }
    }
  }
}

// ---------------- Flash attention (split-KV, tiled K2/V2) — unchanged ---------
__global__ __launch_bounds__(256) void attn_kernel(const _Float16* __restrict__ Q,
                                                   const _Float16* __restrict__ K2,
                                                   const _Float16* __restrict__ V2,
                                                   _Float16* __restrict__ Op,
                                                   float* __restrict__ Md) {
  const int bid = blockIdx.x;
  const int hk = bid & 7;
  const int split = (bid >> 3) & 1;
  const int qt = 63 - (bid >> 4);
  const int w = threadIdx.x >> 6;
  const int h = hk * 4 + w;
  const int l = threadIdx.x & 63;
  const int lr = l & 15;
  const int lg = l >> 4;
  const float scale = 0.08838834764831845f;
  const float LOG2E = 1.4426950408889634f;
  const float NEG = -1.0e30f;

  const int half_steps = qt + 1;
  const int kt0 = split * half_steps;
  const int kt1 = kt0 + half_steps;

  int sq[2];
  half8_t qf[2][4];
#pragma unroll
  for (int qc = 0; qc < 2; ++qc) {
    sq[qc] = qt * 32 + qc * 16 + lr;
#pragma unroll
    for (int c = 0; c < 4; ++c)
      qf[qc][c] = *(const half8_t*)(Q + (size_t)sq[qc] * HID + h * 128 + c * 32 + lg * 8);
  }
  const _Float16* Kb = K2 + (size_t)hk * (S_LEN * 128);
  const _Float16* Vb = V2 + (size_t)hk * (S_LEN * 128);

  f32x4 acc[8][2] = {};
  float m[2] = {NEG, NEG};
  float den[2] = {0.f, 0.f};

  for (int kt = kt0; kt < kt1; ++kt) {
    half8_t kf[4];
#pragma unroll
    for (int c = 0; c < 4; ++c)
      kf[c] = *(const half8_t*)(Kb + (size_t)kt * 2048 + (c * 4 + lg) * 128 + lr * 8);
    f32x4 s0 = {0.f, 0.f, 0.f, 0.f}, s1 = {0.f, 0.f, 0.f, 0.f};
#pragma unroll
    for (int c = 0; c < 4; ++c) {
      s0 = __builtin_amdgcn_mfma_f32_16x16x32_f16(kf[c], qf[0][c], s0, 0, 0, 0);
      s1 = __builtin_amdgcn_mfma_f32_16x16x32_f16(kf[c], qf[1][c], s1, 0, 0, 0);
    }
    const int kbase = kt * 16 + lg * 4;
    float sc[2][4];
#pragma unroll
    for (int i = 0; i < 4; ++i) {
      sc[0][i] = s0[i] * scale;
      sc[1][i] = s1[i] * scale;
    }
    if (kt >= 2 * qt) {
#pragma unroll
      for (int qc = 0; qc < 2; ++qc)
#pragma unroll
        for (int i = 0; i < 4; ++i)
          if (kbase + i > sq[qc]) sc[qc][i] = NEG;
    }
    half4_t pf[2];
#pragma unroll
    for (int qc = 0; qc < 2; ++qc) {
      float mx = fmaxf(fmaxf(sc[qc][0], sc[qc][1]), fmaxf(sc[qc][2], sc[qc][3]));
      mx = fmaxf(mx, __shfl_xor(mx, 16));
      mx = fmaxf(mx, __shfl_xor(mx, 32));
      if (!__all(mx - m[qc] <= 8.0f)) {  // defer-max (T13)
        float mn = fmaxf(m[qc], mx);
        float corr = exp2f((m[qc] - mn) * LOG2E);
        den[qc] *= corr;
#pragma unroll
        for (int dc = 0; dc < 8; ++dc)
#pragma unroll
          for (int i = 0; i < 4; ++i) acc[dc][qc][i] *= corr;
        m[qc] = mn;
      }
      float ps = 0.f, p[4];
#pragma unroll
      for (int i = 0; i < 4; ++i) {
        p[i] = exp2f((sc[qc][i] - m[qc]) * LOG2E);
        ps += p[i];
      }
      ps += __shfl_xor(ps, 16);
      ps += __shfl_xor(ps, 32);
      den[qc] += ps;
      pf[qc] = (half4_t){(_Float16)p[0], (_Float16)p[1], (_Float16)p[2], (_Float16)p[3]};
    }
#pragma unroll
    for (int dc = 0; dc < 8; ++dc) {
      half4_t vf = *(const half4_t*)(Vb + (size_t)kt * 2048 + (dc * 16 + lr) * 16 + lg * 4);
      acc[dc][0] = __builtin_amdgcn_mfma_f32_16x16x16f16(vf, pf[0], acc[dc][0], 0, 0, 0);
      acc[dc][1] = __builtin_amdgcn_mfma_f32_16x16x16f16(vf, pf[1], acc[dc][1], 0, 0, 0);
    }
  }

  _Float16* Os = Op + (size_t)split * S_LEN * HID;
#pragma unroll
  for (int qc = 0; qc < 2; ++qc) {
    float inv = den[qc] > 0.f ? 1.0f / den[qc] : 0.f;
#pragma unroll
    for (int dc = 0; dc < 8; ++dc) {
      half4_t o;
#pragma unroll
      for (int i = 0; i < 4; ++i) o[i] = (_Float16)(acc[dc][qc][i] * inv);
      *(half4_t*)(Os + (size_t)sq[qc] * HID + h * 128 + dc * 16 + lg * 4) = o;
    }
    if (lg == 0) {
      int mdix = ((split * S_LEN + sq[qc]) * NH + h) * 2;
      Md[mdix] = m[qc];
      Md[mdix + 1] = den[qc];
    }
  }
}

// ---------------- split-KV combine ----------------
__global__ __launch_bounds__(256) void attn_combine(const _Float16* __restrict__ Op,
                                                    const float* __restrict__ Md,
                                                    _Float16* __restrict__ O) {
  const float LOG2E = 1.4426950408889634f;
  int idx = blockIdx.x * 256 + threadIdx.x;
  int dd = (idx & 15) * 8;
  int h = (idx >> 4) & 31;
  int s = idx >> 9;
  int base = (s * NH + h) * 2;
  float m0 = Md[base], den0 = Md[base + 1];
  float m1 = Md[S_LEN * NH * 2 + base], den1 = Md[S_LEN * NH * 2 + base + 1];
  float M = fmaxf(m0, m1);
  float w0 = den0 * exp2f((m0 - M) * LOG2E);
  float w1 = den1 * exp2f((m1 - M) * LOG2E);
  float r = 1.0f / (w0 + w1);
  w0 *= r;
  w1 *= r;
  size_t off = (size_t)s * HID + h * 128 + dd;
  half8_t a = *(const half8_t*)(Op + off);
  half8_t b = *(const half8_t*)(Op + (size_t)S_LEN * HID + off);
  half8_t o;
#pragma unroll
  for (int j = 0; j < 8; ++j) o[j] = (_Float16)(w0 * (float)a[j] + w1 * (float)b[j]);
  *(half8_t*)(O + off) = o;
}

// ---------------- launcher ----------------
extern "C" void kernel_launch(void* const* d_in, const int* in_sizes, int n_in,
                              void* d_out, int out_size, void* d_ws, size_t ws_size,
                              hipStream_t stream) {
  (void)in_sizes; (void)n_in; (void)out_size;
  const float* hs = (const float*)d_in[0];
  const float* wq = (const float*)d_in[1];
  const float* wk = (const float*)d_in[2];
  const float* wv = (const float*)d_in[3];
  const float* wo = (const float*)d_in[4];

  char* ws = (char*)d_ws;
  _Float16* hs_h = (_Float16*)(ws);                       // [0,16M): A, later o_h
  _Float16* K2   = (_Float16*)(ws + (32u << 20));         // [32,36M): tiled K
  _Float16* V2   = (_Float16*)(ws + (36u << 20));         // [36,40M): tiled V
  float* cost    = (float*)(ws + (40u << 20));            // 512 KiB
  float* sint    = (float*)(ws + (40u << 20) + (512u << 10));
  _Float16* q_h  = (_Float16*)(ws + (16u << 20));         // [16,32M)
  _Float16* wbuf = (_Float16*)(ws + (41u << 20));         // [41,73M): f16 weights
  _Float16* Op   = wbuf;                                  // attn partials (alias)
  float* Md      = (float*)(ws + (73u << 20));            // [73,75M)
  _Float16* o_h  = hs_h;

  cvt_f32_f16<<<8192, 256, 0, stream>>>(hs, hs_h, (S_LEN * HID) / 4);
  rope_table_kernel<<<(S_LEN * 64) / 256, 256, 0, stream>>>(cost, sint);

  const bool merged = ws_size >= (90ull << 20);
  if (merged) {
    _Float16* wk_h = (_Float16*)(ws + (73u << 20));       // [73,81M)
    _Float16* wv_h = (_Float16*)(ws + (81u << 20));       // [81,89M)
    cvt_f32_f16<<<16384, 256, 0, stream>>>(wq, wbuf, (HID * HID) / 4);
    cvt_f32_f16<<<4096, 256, 0, stream>>>(wk, wk_h, (NKV * 128 * HID) / 4);
    cvt_f32_f16<<<4096, 256, 0, stream>>>(wv, wv_h, (NKV * 128 * HID) / 4);
    gemm5<0><<<dim3(48, 16), 256, 0, stream>>>(hs_h, wbuf, wk_h, wv_h, q_h, K2, V2, 0);
  } else {
    _Float16* wk_h = wbuf;                                // reuse wq space
    _Float16* wv_h = wbuf + (8u << 20) / 2;
    cvt_f32_f16<<<16384, 256, 0, stream>>>(wq, wbuf, (HID * HID) / 4);
    gemm5<0><<<dim3(32, 16), 256, 0, stream>>>(hs_h, wbuf, nullptr, nullptr, q_h, K2, V2, 0);
    cvt_f32_f16<<<4096, 256, 0, stream>>>(wk, wk_h, (NKV * 128 * HID) / 4);
    cvt_f32_f16<<<4096, 256, 0, stream>>>(wv, wv_h, (NKV * 128 * HID) / 4);
    gemm5<0><<<dim3(16, 16), 256, 0, stream>>>(hs_h, nullptr, wk_h, wv_h, q_h, K2, V2, 32);
  }

  rope_apply_q<<<(S_LEN * NH * 16) / 256, 256, 0, stream>>>(q_h, cost, sint);
  rope_k2_inplace<<<(S_LEN * NKV * 16) / 256, 256, 0, stream>>>(K2, cost, sint);

  attn_kernel<<<1024, 256, 0, stream>>>(q_h, K2, V2, Op, Md);
  attn_combine<<<4096, 256, 0, stream>>>(Op, Md, o_h);

  cvt_f32_f16<<<16384, 256, 0, stream>>>(wo, wbuf, (HID * HID) / 4);
  gemm5<1><<<dim3(32, 16), 256, 0, stream>>>(o_h, wbuf, nullptr, nullptr, d_out, nullptr, nullptr, 0);
}

// Round 7
// 399.436 us; speedup vs baseline: 2.1228x; 1.0066x over previous
//
#include <hip/hip_runtime.h>
#include <hip/hip_bf16.h>

// MockLlamaAttention R7: B=1, S=2048, HIDDEN=4096, H=32, HKV=8, D=128, G=4.
// R6 fixed: (1) cvt_qkv grid 6144 -> 24576 (3/4 of merged weights were poison);
// (2) STAGE macros pass an explicitly wave-uniform LDS base to global_load_lds
// (HW semantics: base + lane*16), per-lane swizzled GLOBAL source only.
// GEMMs: 256^2 tile, BK=64, 8 waves, 4-phase interleave, T2 XOR swizzle,
// setprio around MFMA clusters, depth-2 LDS buffer. Attention unchanged.
// Workspace: 89 MiB peak.

typedef _Float16 half4_t __attribute__((ext_vector_type(4)));
typedef _Float16 half8_t __attribute__((ext_vector_type(8)));
typedef float f32x4 __attribute__((ext_vector_type(4)));

#define S_LEN 2048
#define HID 4096
#define NH 32
#define NKV 8

__device__ __forceinline__ void gload_lds16(const void* g, void* l) {
  __builtin_amdgcn_global_load_lds((const __attribute__((address_space(1))) void*)g,
                                   (__attribute__((address_space(3))) void*)l, 16, 0, 0);
}

// ---------------- fp32 -> f16 convert (vectorized) ----------------
__global__ __launch_bounds__(256) void cvt_f32_f16(const float* __restrict__ src,
                                                   _Float16* __restrict__ dst, int n4) {
  int i = blockIdx.x * 256 + threadIdx.x;
  if (i >= n4) return;
  f32x4 v = *(const f32x4*)(src + (size_t)i * 4);
  half4_t h = {(_Float16)v[0], (_Float16)v[1], (_Float16)v[2], (_Float16)v[3]};
  *(half4_t*)(dst + (size_t)i * 4) = h;
}

// ------- merged wq|wk|wv fp32 -> contiguous f16 [6144][4096] -------
__global__ __launch_bounds__(256) void cvt_qkv(const float* __restrict__ wq,
                                               const float* __restrict__ wk,
                                               const float* __restrict__ wv,
                                               _Float16* __restrict__ dst, int n4) {
  int i = blockIdx.x * 256 + threadIdx.x;  // n4 = 6144*4096/4
  if (i >= n4) return;
  size_t e = (size_t)i * 4;
  const float* src;
  size_t off;
  if (e < (size_t)4096 * 4096)      { src = wq; off = e; }
  else if (e < (size_t)5120 * 4096) { src = wk; off = e - (size_t)4096 * 4096; }
  else                              { src = wv; off = e - (size_t)5120 * 4096; }
  f32x4 v = *(const f32x4*)(src + off);
  half4_t h = {(_Float16)v[0], (_Float16)v[1], (_Float16)v[2], (_Float16)v[3]};
  *(half4_t*)(dst + e) = h;
}

// ---------------- RoPE cos/sin table: [2048][64] fp32 ----------------
__global__ __launch_bounds__(256) void rope_table_kernel(float* __restrict__ cost,
                                                         float* __restrict__ sint) {
  int i = blockIdx.x * 256 + threadIdx.x;
  int d = i & 63;
  int s = i >> 6;
  float inv = exp2f(-(float)d * (13.287712379549449f / 64.0f));
  float f = (float)s * inv;
  cost[i] = cosf(f);
  sint[i] = sinf(f);
}

// ---------------- RoPE apply for Q (in place, [S][NH*128]) ----------------
__global__ __launch_bounds__(256) void rope_apply_q(_Float16* __restrict__ X,
                                                    const float* __restrict__ cost,
                                                    const float* __restrict__ sint) {
  int idx = blockIdx.x * 256 + threadIdx.x;
  int g = idx & 15;
  int tmp = idx >> 4;
  int h = tmp % NH;
  int s = tmp / NH;
  int d0 = g * 4;
  size_t base = (size_t)s * HID + h * 128 + d0;
  half4_t x1 = *(half4_t*)(X + base);
  half4_t x2 = *(half4_t*)(X + base + 64);
  const float* cp = cost + s * 64 + d0;
  const float* sp = sint + s * 64 + d0;
  half4_t y1, y2;
#pragma unroll
  for (int j = 0; j < 4; ++j) {
    float c = cp[j], sn = sp[j];
    float a = (float)x1[j], b = (float)x2[j];
    y1[j] = (_Float16)(a * c - b * sn);
    y2[j] = (_Float16)(b * c + a * sn);
  }
  *(half4_t*)(X + base) = y1;
  *(half4_t*)(X + base + 64) = y2;
}

// ------- RoPE apply for K, in place on tiled K2 [NKV][S/16][d/8][16s][8d] ----
__global__ __launch_bounds__(256) void rope_k2_inplace(_Float16* __restrict__ K2,
                                                       const float* __restrict__ cost,
                                                       const float* __restrict__ sint) {
  int idx = blockIdx.x * 256 + threadIdx.x;  // S*NKV*16
  int g = idx & 15;
  int tmp = idx >> 4;
  int h = tmp % NKV;
  int s = tmp / NKV;
  int d0 = g * 4;
  size_t tb = (size_t)h * (S_LEN * 128) + (size_t)(s >> 4) * 2048 + (size_t)(s & 15) * 8;
  size_t a1 = tb + (size_t)(d0 >> 3) * 128 + (d0 & 7);
  size_t a2 = a1 + 1024;
  half4_t x1 = *(half4_t*)(K2 + a1);
  half4_t x2 = *(half4_t*)(K2 + a2);
  const float* cp = cost + s * 64 + d0;
  const float* sp = sint + s * 64 + d0;
  half4_t y1, y2;
#pragma unroll
  for (int j = 0; j < 4; ++j) {
    float c = cp[j], sn = sp[j];
    float a = (float)x1[j], b = (float)x2[j];
    y1[j] = (_Float16)(a * c - b * sn);
    y2[j] = (_Float16)(b * c + a * sn);
  }
  *(half4_t*)(K2 + a1) = y1;
  *(half4_t*)(K2 + a2) = y2;
}

// ======== GEMM: 256x256 tile, BK=64, 8 waves, phase-interleaved ========
// C[M,N] = A[M,4096]f16 @ W[N,4096]f16^T.  Per wave: 128x64 output.
// LDS 128 KiB: As/Bs [2 buf][2 half][128*64], XOR-swizzled (c8 ^= row&7)
// via inverse-swizzled GLOBAL source + linear gload_lds dest + swizzled read.
// MODE 0: QKV epilogue (cols<4096 Q natural, <5120 K2 tiled, else V2 tiled).
// MODE 1: f32 C [2048][4096].
template <int MODE>
__global__ __launch_bounds__(512, 2) void gemm8(const _Float16* __restrict__ A,
                                                const _Float16* __restrict__ W,
                                                void* __restrict__ out,
                                                _Float16* __restrict__ K2,
                                                _Float16* __restrict__ V2) {
  __shared__ __align__(16) _Float16 As[2][2][128 * 64];
  __shared__ __align__(16) _Float16 Bs[2][2][128 * 64];
  const int t = threadIdx.x;
  const int wid = t >> 6, l = t & 63, lr = l & 15, lg = l >> 4;
  const int wm = wid >> 2, wn = wid & 3;
  const int m0 = blockIdx.y * 256, n0 = blockIdx.x * 256;
  const int NT = 4096 / 64;

  const _Float16* Abase = A + (size_t)m0 * 4096;
  const _Float16* Wbase = W + (size_t)n0 * 4096;

  f32x4 acc[8][4] = {};
  half8_t af[4][2], bf[4][2];

  // wave-uniform LDS chunk base; per-lane global source (rule #21: linear LDS
  // dest + inverse-swizzled source; ds_read applies the same XOR).
#define STAGE_A(buf_, kb_)                                                              \
  _Pragma("unroll") for (int hh = 0; hh < 2; ++hh)                                      \
  _Pragma("unroll") for (int j = 0; j < 2; ++j) {                                       \
    const int ciw = j * 512 + wid * 64; /* uniform per wave */                          \
    const int ci = ciw + l;                                                             \
    const int r = ci >> 3, c8 = ci & 7;                                                 \
    gload_lds16(Abase + (size_t)(hh * 128 + r) * 4096 + (kb_) + ((c8 ^ (r & 7)) << 3),  \
                &As[buf_][hh][ciw * 8]);                                                \
  }
#define STAGE_B(buf_, kb_)                                                              \
  _Pragma("unroll") for (int hh = 0; hh < 2; ++hh)                                      \
  _Pragma("unroll") for (int j = 0; j < 2; ++j) {                                       \
    const int ciw = j * 512 + wid * 64;                                                 \
    const int ci = ciw + l;                                                             \
    const int r = ci >> 3, c8 = ci & 7;                                                 \
    gload_lds16(Wbase + (size_t)(hh * 128 + r) * 4096 + (kb_) + ((c8 ^ (r & 7)) << 3),  \
                &Bs[buf_][hh][ciw * 8]);                                                \
  }
#define LDA(mlo_)                                                                       \
  _Pragma("unroll") for (int mi = 0; mi < 4; ++mi)                                      \
  _Pragma("unroll") for (int kk = 0; kk < 2; ++kk) {                                    \
    const int c8 = (kk * 4 + lg) ^ (lr & 7);                                            \
    af[mi][kk] = *(const half8_t*)&As[cur][wm][(((mlo_) + mi) * 16 + lr) * 64 + c8 * 8];\
  }
#define LDB(nlo_)                                                                       \
  _Pragma("unroll") for (int ni = 0; ni < 2; ++ni)                                      \
  _Pragma("unroll") for (int kk = 0; kk < 2; ++kk) {                                    \
    const int c8 = (kk * 4 + lg) ^ (lr & 7);                                            \
    bf[(nlo_) + ni][kk] = *(const half8_t*)&Bs[cur][wn >> 1]                            \
        [((wn & 1) * 64 + ((nlo_) + ni) * 16 + lr) * 64 + c8 * 8];                      \
  }
#define MFMA16(mlo_, nlo_)                                                              \
  _Pragma("unroll") for (int mi = 0; mi < 4; ++mi)                                      \
  _Pragma("unroll") for (int ni = 0; ni < 2; ++ni)                                      \
  _Pragma("unroll") for (int kk = 0; kk < 2; ++kk)                                      \
    acc[(mlo_) + mi][(nlo_) + ni] = __builtin_amdgcn_mfma_f32_16x16x32_f16(             \
        af[mi][kk], bf[(nlo_) + ni][kk], acc[(mlo_) + mi][(nlo_) + ni], 0, 0, 0);

  // prologue: stage tile 0 into buf 0, wait, sync
  STAGE_A(0, 0)
  STAGE_B(0, 0)
  asm volatile("s_waitcnt vmcnt(0)" ::: "memory");
  __builtin_amdgcn_sched_barrier(0);
  __builtin_amdgcn_s_barrier();

  int cur = 0;
  for (int kt = 0; kt < NT; ++kt) {
    const int nkb = (kt + 1) << 6;
    const bool pre = (kt + 1 < NT);
    // phase 0: read a-lo + b-lo, stage next-tile A, MFMA quadrant (0,0)
    LDA(0)
    LDB(0)
    if (pre) { STAGE_A(cur ^ 1, nkb) }
    __builtin_amdgcn_sched_barrier(0);
    __builtin_amdgcn_s_barrier();
    __builtin_amdgcn_s_setprio(1);
    MFMA16(0, 0)
    __builtin_amdgcn_s_setprio(0);
    __builtin_amdgcn_sched_barrier(0);
    __builtin_amdgcn_s_barrier();
    // phase 1: read b-hi, stage next-tile B, MFMA quadrant (0,2)
    LDB(2)
    if (pre) { STAGE_B(cur ^ 1, nkb) }
    __builtin_amdgcn_sched_barrier(0);
    __builtin_amdgcn_s_barrier();
    __builtin_amdgcn_s_setprio(1);
    MFMA16(0, 2)
    __builtin_amdgcn_s_setprio(0);
    __builtin_amdgcn_sched_barrier(0);
    __builtin_amdgcn_s_barrier();
    // phase 2: read a-hi, MFMA quadrant (4,2)
    LDA(4)
    __builtin_amdgcn_sched_barrier(0);
    __builtin_amdgcn_s_barrier();
    __builtin_amdgcn_s_setprio(1);
    MFMA16(4, 2)
    __builtin_amdgcn_s_setprio(0);
    __builtin_amdgcn_sched_barrier(0);
    __builtin_amdgcn_s_barrier();
    // phase 3: MFMA quadrant (4,0); ensure next tile landed before swap
    __builtin_amdgcn_s_setprio(1);
    MFMA16(4, 0)
    __builtin_amdgcn_s_setprio(0);
    asm volatile("s_waitcnt vmcnt(0)" ::: "memory");
    __builtin_amdgcn_sched_barrier(0);
    __builtin_amdgcn_s_barrier();
    cur ^= 1;
  }
#undef STAGE_A
#undef STAGE_B
#undef LDA
#undef LDB
#undef MFMA16

  // epilogue
  const int grow0 = m0 + wm * 128;
  const int gcol0 = n0 + wn * 64;
#pragma unroll
  for (int mi = 0; mi < 8; ++mi) {
#pragma unroll
    for (int ni = 0; ni < 4; ++ni) {
      const int row = grow0 + mi * 16 + lg * 4;
      const int col = gcol0 + ni * 16 + lr;
      if (MODE == 1) {
#pragma unroll
        for (int i = 0; i < 4; ++i)
          ((float*)out)[(size_t)(row + i) * 4096 + col] = acc[mi][ni][i];
      } else {
        if (col < 4096) {
#pragma unroll
          for (int i = 0; i < 4; ++i)
            ((_Float16*)out)[(size_t)(row + i) * 4096 + col] = (_Float16)acc[mi][ni][i];
        } else if (col < 5120) {  // K2 tiled [NKV][S/16][d/8][16s][8d]
          const int c = col - 4096;
          const int h = c >> 7, d = c & 127;
          const size_t kb2 = (size_t)h * (S_LEN * 128) + (size_t)(row >> 4) * 2048 +
                             (size_t)(d >> 3) * 128 + (d & 7);
#pragma unroll
          for (int i = 0; i < 4; ++i)
            K2[kb2 + ((row + i) & 15) * 8] = (_Float16)acc[mi][ni][i];
        } else {  // V2 tiled [NKV][S/16][128d][16s]
          const int c = col - 5120;
          half4_t o;
#pragma unroll
          for (int i = 0; i < 4; ++i) o[i] = (_Float16)acc[mi][ni][i];
          *(half4_t*)(V2 + (size_t)(c >> 7) * (S_LEN * 128) + (size_t)(row >> 4) * 2048 +
                      (size_t)(c & 127) * 16 + (row & 15)) = o;
        }
      }
    }
  }
}

// ---------------- Flash attention (split-KV, tiled K2/V2) — unchanged ---------
__global__ __launch_bounds__(256) void attn_kernel(const _Float16* __restrict__ Q,
                                                   const _Float16* __restrict__ K2,
                                                   const _Float16* __restrict__ V2,
                                                   _Float16* __restrict__ Op,
                                                   float* __restrict__ Md) {
  const int bid = blockIdx.x;
  const int hk = bid & 7;
  const int split = (bid >> 3) & 1;
  const int qt = 63 - (bid >> 4);
  const int w = threadIdx.x >> 6;
  const int h = hk * 4 + w;
  const int l = threadIdx.x & 63;
  const int lr = l & 15;
  const int lg = l >> 4;
  const float scale = 0.08838834764831845f;
  const float LOG2E = 1.4426950408889634f;
  const float NEG = -1.0e30f;

  const int half_steps = qt + 1;
  const int kt0 = split * half_steps;
  const int kt1 = kt0 + half_steps;

  int sq[2];
  half8_t qf[2][4];
#pragma unroll
  for (int qc = 0; qc < 2; ++qc) {
    sq[qc] = qt * 32 + qc * 16 + lr;
#pragma unroll
    for (int c = 0; c < 4; ++c)
      qf[qc][c] = *(const half8_t*)(Q + (size_t)sq[qc] * HID + h * 128 + c * 32 + lg * 8);
  }
  const _Float16* Kb = K2 + (size_t)hk * (S_LEN * 128);
  const _Float16* Vb = V2 + (size_t)hk * (S_LEN * 128);

  f32x4 acc[8][2] = {};
  float m[2] = {NEG, NEG};
  float den[2] = {0.f, 0.f};

  for (int kt = kt0; kt < kt1; ++kt) {
    half8_t kf[4];
#pragma unroll
    for (int c = 0; c < 4; ++c)
      kf[c] = *(const half8_t*)(Kb + (size_t)kt * 2048 + (c * 4 + lg) * 128 + lr * 8);
    f32x4 s0 = {0.f, 0.f, 0.f, 0.f}, s1 = {0.f, 0.f, 0.f, 0.f};
#pragma unroll
    for (int c = 0; c < 4; ++c) {
      s0 = __builtin_amdgcn_mfma_f32_16x16x32_f16(kf[c], qf[0][c], s0, 0, 0, 0);
      s1 = __builtin_amdgcn_mfma_f32_16x16x32_f16(kf[c], qf[1][c], s1, 0, 0, 0);
    }
    const int kbase = kt * 16 + lg * 4;
    float sc[2][4];
#pragma unroll
    for (int i = 0; i < 4; ++i) {
      sc[0][i] = s0[i] * scale;
      sc[1][i] = s1[i] * scale;
    }
    if (kt >= 2 * qt) {
#pragma unroll
      for (int qc = 0; qc < 2; ++qc)
#pragma unroll
        for (int i = 0; i < 4; ++i)
          if (kbase + i > sq[qc]) sc[qc][i] = NEG;
    }
    half4_t pf[2];
#pragma unroll
    for (int qc = 0; qc < 2; ++qc) {
      float mx = fmaxf(fmaxf(sc[qc][0], sc[qc][1]), fmaxf(sc[qc][2], sc[qc][3]));
      mx = fmaxf(mx, __shfl_xor(mx, 16));
      mx = fmaxf(mx, __shfl_xor(mx, 32));
      if (!__all(mx - m[qc] <= 8.0f)) {  // defer-max (T13)
        float mn = fmaxf(m[qc], mx);
        float corr = exp2f((m[qc] - mn) * LOG2E);
        den[qc] *= corr;
#pragma unroll
        for (int dc = 0; dc < 8; ++dc)
#pragma unroll
          for (int i = 0; i < 4; ++i) acc[dc][qc][i] *= corr;
        m[qc] = mn;
      }
      float ps = 0.f, p[4];
#pragma unroll
      for (int i = 0; i < 4; ++i) {
        p[i] = exp2f((sc[qc][i] - m[qc]) * LOG2E);
        ps += p[i];
      }
      ps += __shfl_xor(ps, 16);
      ps += __shfl_xor(ps, 32);
      den[qc] += ps;
      pf[qc] = (half4_t){(_Float16)p[0], (_Float16)p[1], (_Float16)p[2], (_Float16)p[3]};
    }
#pragma unroll
    for (int dc = 0; dc < 8; ++dc) {
      half4_t vf = *(const half4_t*)(Vb + (size_t)kt * 2048 + (dc * 16 + lr) * 16 + lg * 4);
      acc[dc][0] = __builtin_amdgcn_mfma_f32_16x16x16f16(vf, pf[0], acc[dc][0], 0, 0, 0);
      acc[dc][1] = __builtin_amdgcn_mfma_f32_16x16x16f16(vf, pf[1], acc[dc][1], 0, 0, 0);
    }
  }

  _Float16* Os = Op + (size_t)split * S_LEN * HID;
#pragma unroll
  for (int qc = 0; qc < 2; ++qc) {
    float inv = den[qc] > 0.f ? 1.0f / den[qc] : 0.f;
#pragma unroll
    for (int dc = 0; dc < 8; ++dc) {
      half4_t o;
#pragma unroll
      for (int i = 0; i < 4; ++i) o[i] = (_Float16)(acc[dc][qc][i] * inv);
      *(half4_t*)(Os + (size_t)sq[qc] * HID + h * 128 + dc * 16 + lg * 4) = o;
    }
    if (lg == 0) {
      int mdix = ((split * S_LEN + sq[qc]) * NH + h) * 2;
      Md[mdix] = m[qc];
      Md[mdix + 1] = den[qc];
    }
  }
}

// ---------------- split-KV combine ----------------
__global__ __launch_bounds__(256) void attn_combine(const _Float16* __restrict__ Op,
                                                    const float* __restrict__ Md,
                                                    _Float16* __restrict__ O) {
  const float LOG2E = 1.4426950408889634f;
  int idx = blockIdx.x * 256 + threadIdx.x;
  int dd = (idx & 15) * 8;
  int h = (idx >> 4) & 31;
  int s = idx >> 9;
  int base = (s * NH + h) * 2;
  float m0 = Md[base], den0 = Md[base + 1];
  float m1 = Md[S_LEN * NH * 2 + base], den1 = Md[S_LEN * NH * 2 + base + 1];
  float M = fmaxf(m0, m1);
  float w0 = den0 * exp2f((m0 - M) * LOG2E);
  float w1 = den1 * exp2f((m1 - M) * LOG2E);
  float r = 1.0f / (w0 + w1);
  w0 *= r;
  w1 *= r;
  size_t off = (size_t)s * HID + h * 128 + dd;
  half8_t a = *(const half8_t*)(Op + off);
  half8_t b = *(const half8_t*)(Op + (size_t)S_LEN * HID + off);
  half8_t o;
#pragma unroll
  for (int j = 0; j < 8; ++j) o[j] = (_Float16)(w0 * (float)a[j] + w1 * (float)b[j]);
  *(half8_t*)(O + off) = o;
}

// ---------------- launcher ----------------
extern "C" void kernel_launch(void* const* d_in, const int* in_sizes, int n_in,
                              void* d_out, int out_size, void* d_ws, size_t ws_size,
                              hipStream_t stream) {
  (void)in_sizes; (void)n_in; (void)out_size; (void)ws_size;
  const float* hs = (const float*)d_in[0];
  const float* wq = (const float*)d_in[1];
  const float* wk = (const float*)d_in[2];
  const float* wv = (const float*)d_in[3];
  const float* wo = (const float*)d_in[4];

  char* ws = (char*)d_ws;
  _Float16* hs_h = (_Float16*)(ws);                       // [0,16M): hs f16; later o_h
  _Float16* q_h  = (_Float16*)(ws + (16u << 20));         // [16,32M)
  _Float16* K2   = (_Float16*)(ws + (32u << 20));         // [32,36M): tiled K
  _Float16* V2   = (_Float16*)(ws + (36u << 20));         // [36,40M): tiled V
  float* cost    = (float*)(ws + (40u << 20));            // 512 KiB
  float* sint    = (float*)(ws + (40u << 20) + (512u << 10));
  _Float16* wqkv = (_Float16*)(ws + (41u << 20));         // [41,89M): merged f16 weights
  _Float16* Op   = wqkv;                                  // [41,73M): attn partials (wqkv dead)
  float* Md      = (float*)(ws + (73u << 20));            // [73,75M)
  _Float16* wo_h = wqkv;                                  // [41,73M): wo f16 (Op dead)
  _Float16* o_h  = hs_h;

  cvt_f32_f16<<<8192, 256, 0, stream>>>(hs, hs_h, (S_LEN * HID) / 4);
  rope_table_kernel<<<(S_LEN * 64) / 256, 256, 0, stream>>>(cost, sint);
  cvt_qkv<<<24576, 256, 0, stream>>>(wq, wk, wv, wqkv, (6144 * 4096) / 4);

  // merged QKV projection: 24 col-tiles (16 Q, 4 K, 4 V) x 8 row-tiles
  gemm8<0><<<dim3(24, 8), 512, 0, stream>>>(hs_h, wqkv, q_h, K2, V2);

  rope_apply_q<<<(S_LEN * NH * 16) / 256, 256, 0, stream>>>(q_h, cost, sint);
  rope_k2_inplace<<<(S_LEN * NKV * 16) / 256, 256, 0, stream>>>(K2, cost, sint);

  attn_kernel<<<1024, 256, 0, stream>>>(q_h, K2, V2, Op, Md);
  attn_combine<<<4096, 256, 0, stream>>>(Op, Md, o_h);

  cvt_f32_f16<<<16384, 256, 0, stream>>>(wo, wo_h, (HID * HID) / 4);
  gemm8<1><<<dim3(16, 8), 512, 0, stream>>>(o_h, wo_h, d_out, nullptr, nullptr);
}